// Round 13
// baseline (796.717 us; speedup 1.0000x reference)
//
#include <hip/hip_runtime.h>
#include <hip/hip_bf16.h>
#include <hip/amd_detail/amd_hip_vector_types.h>

#define NPTS 8192
#define PP 2048
#define KNN 30
#define KTOT 31
#define HEADS 3
#define LDH 352   // padded ld for link4 hi/lo (bf16): >= Kpad32(326), mult of 8
#define NSEG 10

typedef __attribute__((ext_vector_type(8))) short short8;
typedef __attribute__((ext_vector_type(4))) float floatx4;
typedef __attribute__((ext_vector_type(4))) unsigned int uint4_t;
typedef unsigned short ushort_t;
typedef unsigned int uint_t;

__device__ inline ushort_t f2bs(float v) {
    __hip_bfloat16 b = __float2bfloat16(v);
    return *reinterpret_cast<ushort_t*>(&b);
}
__device__ inline float bs2f(ushort_t u) {
    __hip_bfloat16 b = *reinterpret_cast<__hip_bfloat16*>(&u);
    return __bfloat162float(b);
}
__device__ inline void split2(float v, ushort_t& h, ushort_t& l) {
    h = f2bs(v);
    l = f2bs(v - bs2f(h));
}

// ---------------- build x0 (hi/lo) into link4 cols 0..5 ----------------
__global__ void k_build_x0(const float* __restrict__ x, const float* __restrict__ pos,
                           ushort_t* __restrict__ lh, ushort_t* __restrict__ ll) {
    int i = blockIdx.x * blockDim.x + threadIdx.x;
    if (i >= NPTS * 6) return;
    int n = i / 6, c = i % 6;
    float v = (c < 3) ? x[n * 3 + c] : pos[n * 3 + (c - 3)];
    ushort_t h, l; split2(v, h, l);
    lh[(size_t)n * LDH + c] = h;
    ll[(size_t)n * LDH + c] = l;
}

// ---------------- per-row squared norms from hi/lo ----------------
__global__ void k_sqnorm(const ushort_t* __restrict__ lh, const ushort_t* __restrict__ ll,
                         int co, int C, float* __restrict__ sq) {
    int n = blockIdx.x * blockDim.x + threadIdx.x;
    if (n >= NPTS) return;
    const ushort_t* ph = lh + (size_t)n * LDH + co;
    const ushort_t* pl = ll + (size_t)n * LDH + co;
    float s = 0.f;
    for (int c = 0; c < C; c++) { float v = bs2f(ph[c]) + bs2f(pl[c]); s += v * v; }
    sq[n] = s;
}

// ---------------- fused stage-1 KNN (C=6): cloud slab in LDS, exact fp32 ----------
// one block per 4 rows; wave per row; 2048 distances in registers -> packed top-30.
__global__ __launch_bounds__(256)
void k_knn6(const float* __restrict__ x, const float* __restrict__ pos,
            int* __restrict__ nbr) {
    __shared__ float Fs[6][PP];
    __shared__ float Sq[PP];
    int blk = blockIdx.x;
    int b = blk / (PP / 4);
    int r0 = (blk % (PP / 4)) * 4;
    int cb = b * PP;
    int t = threadIdx.x;
    for (int idx = t; idx < 6 * PP; idx += 256) {
        int c = idx / PP, j = idx % PP;
        Fs[c][j] = (c < 3) ? x[(size_t)(cb + j) * 3 + c]
                           : pos[(size_t)(cb + j) * 3 + (c - 3)];
    }
    __syncthreads();
    for (int j = t; j < PP; j += 256) {
        float s = 0.f;
#pragma unroll
        for (int c = 0; c < 6; c++) { float v = Fs[c][j]; s += v * v; }
        Sq[j] = s;
    }
    __syncthreads();
    int w = t >> 6, lane = t & 63;
    int r = r0 + w;
    float rf[6];
#pragma unroll
    for (int c = 0; c < 6; c++) rf[c] = Fs[c][r];
    float rsq = Sq[r];
    uint_t v[32];
#pragma unroll
    for (int i = 0; i < 32; i++) {
        int j = (i << 6) | lane;   // col = i*64 + lane; group = col>>8 = i>>2
        float dot = 0.f;
#pragma unroll
        for (int c = 0; c < 6; c++) dot = fmaf(rf[c], Fs[c][j], dot);
        float dd = rsq + Sq[j] - 2.f * dot;
        dd = (j == r) ? 3e9f : fmaxf(dd, 0.f);
        v[i] = (__float_as_uint(dd) & 0xFFFFF800u) | (uint_t)j;
    }
    uint_t g[8];
#pragma unroll
    for (int gi = 0; gi < 8; gi++)
        g[gi] = min(min(v[gi * 4], v[gi * 4 + 1]), min(v[gi * 4 + 2], v[gi * 4 + 3]));
    uint_t lv = g[0];
#pragma unroll
    for (int gi = 1; gi < 8; gi++) lv = min(lv, g[gi]);
    for (int sel = 0; sel < KNN; sel++) {
        uint_t bk = lv;
#pragma unroll
        for (int off = 32; off > 0; off >>= 1)
            bk = min(bk, (uint_t)__shfl_xor((int)bk, off, 64));
        uint_t bks = __builtin_amdgcn_readfirstlane(bk);
        if (lane == 0) nbr[(size_t)(cb + r) * KTOT + sel] = cb + (int)(bks & 0x7FFu);
        int grp = (int)((bks & 0x7FFu) >> 8);
#pragma unroll
        for (int jj = 0; jj < 8; jj++)
            if (grp == jj) {
#pragma unroll
                for (int q = 0; q < 4; q++)
                    v[jj * 4 + q] = (v[jj * 4 + q] == bks) ? 0xFFFFFFFFu : v[jj * 4 + q];
                g[jj] = min(min(v[jj * 4], v[jj * 4 + 1]), min(v[jj * 4 + 2], v[jj * 4 + 3]));
            }
        lv = g[0];
#pragma unroll
        for (int gi = 1; gi < 8; gi++) lv = min(lv, g[gi]);
    }
    if (lane == 0) nbr[(size_t)(cb + r) * KTOT + KNN] = cb + r;
}

// ---------------- fused weight transpose + split (10 MFMA weights, one launch) ----------
struct WArgs {
    const float* src[NSEG];
    ushort_t* dst[NSEG];
    int K[NSEG], N[NSEG], Kp[NSEG], t0[NSEG];
};
__global__ void k_wsplit_all(WArgs a) {
    int bt = blockIdx.x;
    int si = 0;
#pragma unroll
    for (int i = 1; i < NSEG; i++) if (bt >= a.t0[i]) si = i;
    int t = bt - a.t0[si];
    int K_ = a.K[si], N_ = a.N[si], Kp = a.Kp[si];
    const float* src = a.src[si];
    ushort_t* dh = a.dst[si];
    ushort_t* dl = dh + (size_t)Kp * N_;
    int tX = (N_ + 31) >> 5;
    int k0 = (t / tX) * 32, n0 = (t % tX) * 32;
    __shared__ float tt[32][33];
    int c = threadIdx.x & 31, r8 = threadIdx.x >> 5;
#pragma unroll
    for (int i = 0; i < 4; i++) {
        int r = r8 + i * 8;
        int k = k0 + r, n = n0 + c;
        tt[r][c] = (k < K_ && n < N_) ? src[(size_t)k * N_ + n] : 0.f;
    }
    __syncthreads();
#pragma unroll
    for (int i = 0; i < 4; i++) {
        int r = r8 + i * 8;
        int n = n0 + r, k = k0 + c;
        if (n < N_) {
            float v = tt[c][r];
            ushort_t h, l; split2(v, h, l);
            dh[(size_t)n * Kp + k] = h;
            dl[(size_t)n * Kp + k] = l;
        }
    }
}

// -------- pure-bf16 MFMA GEMM, software-pipelined; optional fused log_softmax ------
template<int MT, int NT>
__global__ __launch_bounds__(256)
void k_mgemm1(const ushort_t* __restrict__ A, int lda,
              const ushort_t* __restrict__ W, int ldw,
              float* __restrict__ Cf, int ldc,
              ushort_t* __restrict__ Ch, int ldh,
              int Ndim, int K,
              const float* __restrict__ bias1, const float* __restrict__ bias2,
              int relu, int lsm) {
    constexpr int MTW = MT / 64;
    constexpr int NTT = NT / 16;
    __shared__ ushort_t As[2][MT * 40];
    __shared__ ushort_t Bs[2][NT * 40];
    int tid = threadIdx.x;
    int w = tid >> 6, lane = tid & 63;
    int quad = lane >> 4, l16 = lane & 15;
    int m0 = blockIdx.x * MT, n0 = blockIdx.y * NT;
    uint4_t pa[MT / 64], pb[NT / 64];
    auto prefetch = [&](int k0) {
#pragma unroll
        for (int rep = 0; rep < MT / 64; rep++) {
            int idx = tid + rep * 256;
            int row = idx >> 2, q = idx & 3;
            pa[rep] = *(const uint4_t*)(A + (size_t)(m0 + row) * lda + k0 + q * 8);
        }
#pragma unroll
        for (int rep = 0; rep < NT / 64; rep++) {
            int idx = tid + rep * 256;
            int row = idx >> 2, q = idx & 3;
            uint4_t v = {0, 0, 0, 0};
            if (n0 + row < Ndim) v = *(const uint4_t*)(W + (size_t)(n0 + row) * ldw + k0 + q * 8);
            pb[rep] = v;
        }
    };
    auto stage = [&](int buf) {
#pragma unroll
        for (int rep = 0; rep < MT / 64; rep++) {
            int idx = tid + rep * 256;
            int row = idx >> 2, q = idx & 3;
            *(uint4_t*)&As[buf][row * 40 + q * 8] = pa[rep];
        }
#pragma unroll
        for (int rep = 0; rep < NT / 64; rep++) {
            int idx = tid + rep * 256;
            int row = idx >> 2, q = idx & 3;
            *(uint4_t*)&Bs[buf][row * 40 + q * 8] = pb[rep];
        }
    };
    floatx4 acc[MTW][NTT] = {};
    prefetch(0);
    stage(0);
    __syncthreads();
    int cur = 0;
    for (int k0 = 0; k0 < K; k0 += 32) {
        bool more = (k0 + 32 < K);
        if (more) prefetch(k0 + 32);
        short8 ah[MTW];
#pragma unroll
        for (int mt = 0; mt < MTW; mt++) {
            int r = w * (MT / 4) + mt * 16 + l16;
            ah[mt] = *(short8*)&As[cur][r * 40 + quad * 8];
        }
#pragma unroll
        for (int nt = 0; nt < NTT; nt++) {
            int r = nt * 16 + l16;
            short8 bh = *(short8*)&Bs[cur][r * 40 + quad * 8];
#pragma unroll
            for (int mt = 0; mt < MTW; mt++)
                acc[mt][nt] = __builtin_amdgcn_mfma_f32_16x16x32_bf16(ah[mt], bh, acc[mt][nt], 0, 0, 0);
        }
        if (more) stage(cur ^ 1);
        __syncthreads();
        cur ^= 1;
    }
    if (lsm) {
        // fused log_softmax over Ndim (<= NT) cols; whole row lives in this block
#pragma unroll
        for (int mt = 0; mt < MTW; mt++) {
#pragma unroll
            for (int r = 0; r < 4; r++) {
                float vv[NTT];
                float mrow = -3e38f;
#pragma unroll
                for (int nt = 0; nt < NTT; nt++) {
                    int n = n0 + nt * 16 + l16;
                    float val = (n < Ndim) ? acc[mt][nt][r] + bias1[n] : -3e38f;
                    vv[nt] = val;
                    mrow = fmaxf(mrow, val);
                }
#pragma unroll
                for (int off = 8; off >= 1; off >>= 1)
                    mrow = fmaxf(mrow, __shfl_xor(mrow, off, 64));
                float s = 0.f;
#pragma unroll
                for (int nt = 0; nt < NTT; nt++)
                    if (vv[nt] > -1e38f) s += expf(vv[nt] - mrow);
#pragma unroll
                for (int off = 8; off >= 1; off >>= 1)
                    s += __shfl_xor(s, off, 64);
                float lse = mrow + logf(s);
                int m = m0 + w * (MT / 4) + mt * 16 + quad * 4 + r;
#pragma unroll
                for (int nt = 0; nt < NTT; nt++) {
                    int n = n0 + nt * 16 + l16;
                    if (n < Ndim) Cf[(size_t)m * ldc + n] = vv[nt] - lse;
                }
            }
        }
        return;
    }
#pragma unroll
    for (int mt = 0; mt < MTW; mt++) {
#pragma unroll
        for (int nt = 0; nt < NTT; nt++) {
#pragma unroll
            for (int r = 0; r < 4; r++) {
                int m = m0 + w * (MT / 4) + mt * 16 + quad * 4 + r;
                int n = n0 + nt * 16 + l16;
                if (n < Ndim) {
                    float v = acc[mt][nt][r];
                    if (bias1) v += bias1[n];
                    if (bias2) v += bias2[n];
                    if (relu && v < 0.f) v = 0.f;
                    if (Cf) Cf[(size_t)m * ldc + n] = v;
                    if (Ch) Ch[(size_t)m * ldh + n] = f2bs(v);
                }
            }
        }
    }
}

// ---------------- split-bf16 (3-term) MFMA GEMM, single-buffered (small K only) -----
__global__ __launch_bounds__(256)
void k_mgemm3(const ushort_t* __restrict__ Ah, const ushort_t* __restrict__ Al, int lda,
              const ushort_t* __restrict__ Wh, const ushort_t* __restrict__ Wl, int ldw,
              float* __restrict__ Cf, int ldc,
              int Ndim, int K) {
    constexpr int NTT = 4;
    __shared__ ushort_t AsH[64 * 40], BsH[64 * 40], AsL[64 * 40], BsL[64 * 40];
    int tid = threadIdx.x;
    int w = tid >> 6, lane = tid & 63;
    int quad = lane >> 4, l16 = lane & 15;
    int m0 = blockIdx.y * 64, n0 = blockIdx.x * 64;
    floatx4 acc[NTT] = {};
    for (int k0 = 0; k0 < K; k0 += 32) {
        {
            int row = tid >> 2, q = tid & 3;
            size_t go = (size_t)(m0 + row) * lda + k0 + q * 8;
            *(uint4_t*)&AsH[row * 40 + q * 8] = *(const uint4_t*)(Ah + go);
            *(uint4_t*)&AsL[row * 40 + q * 8] = *(const uint4_t*)(Al + go);
            uint4_t vh = {0, 0, 0, 0}, vl = {0, 0, 0, 0};
            size_t gw = (size_t)(n0 + row) * ldw + k0 + q * 8;
            if (n0 + row < Ndim) { vh = *(const uint4_t*)(Wh + gw); vl = *(const uint4_t*)(Wl + gw); }
            *(uint4_t*)&BsH[row * 40 + q * 8] = vh;
            *(uint4_t*)&BsL[row * 40 + q * 8] = vl;
        }
        __syncthreads();
        short8 ah, al;
        {
            int r = w * 16 + l16;
            ah = *(short8*)&AsH[r * 40 + quad * 8];
            al = *(short8*)&AsL[r * 40 + quad * 8];
        }
#pragma unroll
        for (int nt = 0; nt < NTT; nt++) {
            int r = nt * 16 + l16;
            short8 bh = *(short8*)&BsH[r * 40 + quad * 8];
            short8 bl = *(short8*)&BsL[r * 40 + quad * 8];
            acc[nt] = __builtin_amdgcn_mfma_f32_16x16x32_bf16(ah, bh, acc[nt], 0, 0, 0);
            acc[nt] = __builtin_amdgcn_mfma_f32_16x16x32_bf16(ah, bl, acc[nt], 0, 0, 0);
            acc[nt] = __builtin_amdgcn_mfma_f32_16x16x32_bf16(al, bh, acc[nt], 0, 0, 0);
        }
        __syncthreads();
    }
#pragma unroll
    for (int nt = 0; nt < NTT; nt++) {
#pragma unroll
        for (int r = 0; r < 4; r++) {
            int m = m0 + w * 16 + quad * 4 + r;
            int n = n0 + nt * 16 + l16;
            if (n < Ndim) Cf[(size_t)m * ldc + n] = acc[nt][r];
        }
    }
}

// ---------------- exact-fp32 VALU GEMM for small N, K%64==0: LDS-tiled W ----------
template<int N_, int NPB>
__global__ __launch_bounds__(NPB * N_)
void k_vgemm(const float* __restrict__ A, int lda, int K_,
             const float* __restrict__ W, const float* __restrict__ bias,
             ushort_t* __restrict__ Ch, ushort_t* __restrict__ Cl, int ldh,
             float* __restrict__ Cf, int ldc, int relu) {
    constexpr int KT = 64;
    __shared__ float Ws[KT * N_];
    __shared__ float As[NPB * KT];
    int t = threadIdx.x;
    int n0 = blockIdx.x * NPB;
    int node = t / N_, j = t % N_;
    float acc = bias ? bias[j] : 0.f;
    for (int k0 = 0; k0 < K_; k0 += KT) {
        for (int idx = t; idx < KT * N_; idx += NPB * N_)
            Ws[idx] = W[(size_t)(k0 + idx / N_) * N_ + idx % N_];
        for (int idx = t; idx < NPB * KT; idx += NPB * N_)
            As[idx] = A[(size_t)(n0 + idx / KT) * lda + k0 + idx % KT];
        __syncthreads();
#pragma unroll
        for (int kk = 0; kk < KT; kk++)
            acc += As[node * KT + kk] * Ws[kk * N_ + j];
        __syncthreads();
    }
    if (relu && acc < 0.f) acc = 0.f;
    size_t m = n0 + node;
    if (Cf) Cf[m * ldc + j] = acc;
    if (Ch) {
        ushort_t h = f2bs(acc);
        Ch[m * ldh + j] = h;
        if (Cl) Cl[m * ldh + j] = f2bs(acc - bs2f(h));
    }
}

// ---------------- tw1: xh = [x|pos] @ w1, exact fp32 (K=6) ----------------
__global__ void k_tw1(const float* __restrict__ x, const float* __restrict__ pos,
                      const float* __restrict__ w1, float* __restrict__ xh) {
    int t = blockIdx.x * blockDim.x + threadIdx.x;
    if (t >= NPTS * 192) return;
    int n = t / 192, j = t % 192;
    float acc = 0.f;
#pragma unroll
    for (int c = 0; c < 3; c++) {
        acc += x[n * 3 + c] * w1[c * 192 + j];
        acc += pos[n * 3 + c] * w1[(3 + c) * 192 + j];
    }
    xh[(size_t)n * 192 + j] = acc;
}

// ---------------- split-bf16 MFMA pairwise distances -> packed sort keys ----------------
__global__ __launch_bounds__(256)
void k_mdist(const ushort_t* __restrict__ Lh, const ushort_t* __restrict__ Ll,
             int co, int C, const float* __restrict__ sq, uint_t* __restrict__ keys) {
    __shared__ ushort_t AsH[128 * 40], AsL[128 * 40], BsH[64 * 40], BsL[64 * 40];
    int tid = threadIdx.x;
    int w = tid >> 6, lane = tid & 63;
    int quad = lane >> 4, l16 = lane & 15;
    int b = blockIdx.z, cb = b * PP;
    int i0 = blockIdx.y * 128, j0 = blockIdx.x * 64;
    floatx4 acc[2][4] = {};
    for (int k0 = 0; k0 < C; k0 += 32) {
#pragma unroll
        for (int rep = 0; rep < 8; rep++) {
            int d = tid + rep * 256;
            int row = d >> 4, c2 = d & 15;
            size_t gi = ((size_t)(cb + i0 + row) * LDH + co + k0 + c2 * 2) >> 1;
            *(uint_t*)&AsH[row * 40 + c2 * 2] = ((const uint_t*)Lh)[gi];
            *(uint_t*)&AsL[row * 40 + c2 * 2] = ((const uint_t*)Ll)[gi];
        }
#pragma unroll
        for (int rep = 0; rep < 4; rep++) {
            int d = tid + rep * 256;
            int row = d >> 4, c2 = d & 15;
            size_t gi = ((size_t)(cb + j0 + row) * LDH + co + k0 + c2 * 2) >> 1;
            *(uint_t*)&BsH[row * 40 + c2 * 2] = ((const uint_t*)Lh)[gi];
            *(uint_t*)&BsL[row * 40 + c2 * 2] = ((const uint_t*)Ll)[gi];
        }
        __syncthreads();
        short8 ah[2], al[2];
#pragma unroll
        for (int mt = 0; mt < 2; mt++) {
            int r = w * 32 + mt * 16 + l16;
            ah[mt] = *(short8*)&AsH[r * 40 + quad * 8];
            al[mt] = *(short8*)&AsL[r * 40 + quad * 8];
        }
#pragma unroll
        for (int nt = 0; nt < 4; nt++) {
            int r = nt * 16 + l16;
            short8 bh = *(short8*)&BsH[r * 40 + quad * 8];
            short8 bl = *(short8*)&BsL[r * 40 + quad * 8];
#pragma unroll
            for (int mt = 0; mt < 2; mt++) {
                acc[mt][nt] = __builtin_amdgcn_mfma_f32_16x16x32_bf16(ah[mt], bh, acc[mt][nt], 0, 0, 0);
                acc[mt][nt] = __builtin_amdgcn_mfma_f32_16x16x32_bf16(ah[mt], bl, acc[mt][nt], 0, 0, 0);
                acc[mt][nt] = __builtin_amdgcn_mfma_f32_16x16x32_bf16(al[mt], bh, acc[mt][nt], 0, 0, 0);
            }
        }
        __syncthreads();
    }
#pragma unroll
    for (int mt = 0; mt < 2; mt++) {
#pragma unroll
        for (int nt = 0; nt < 4; nt++) {
#pragma unroll
            for (int r = 0; r < 4; r++) {
                int il = i0 + w * 32 + mt * 16 + quad * 4 + r;
                int jl = j0 + nt * 16 + l16;
                float dd = sq[cb + il] + sq[cb + jl] - 2.f * acc[mt][nt][r];
                dd = (il == jl) ? 3e9f : fmaxf(dd, 0.f);
                keys[(size_t)(cb + il) * PP + jl] =
                    (__float_as_uint(dd) & 0xFFFFF800u) | (uint_t)jl;
            }
        }
    }
}

// ---------------- top-30 smallest per row via packed u32 keys ----------------
__global__ __launch_bounds__(256)
void k_topk(const uint_t* __restrict__ keys, int* __restrict__ nbr) {
    int r = blockIdx.x * 4 + (threadIdx.x >> 6);
    int lane = threadIdx.x & 63;
    int base = (r / PP) * PP;
    const uint_t* row = keys + (size_t)r * PP;
    uint_t v[32];
#pragma unroll
    for (int j = 0; j < 8; j++)
        *(uint4_t*)&v[j * 4] = *(const uint4_t*)(row + lane * 4 + j * 256);
    uint_t g[8];
#pragma unroll
    for (int j = 0; j < 8; j++)
        g[j] = min(min(v[j * 4], v[j * 4 + 1]), min(v[j * 4 + 2], v[j * 4 + 3]));
    uint_t lv = g[0];
#pragma unroll
    for (int j = 1; j < 8; j++) lv = min(lv, g[j]);
    for (int sel = 0; sel < KNN; sel++) {
        uint_t bk = lv;
#pragma unroll
        for (int off = 32; off > 0; off >>= 1)
            bk = min(bk, (uint_t)__shfl_xor((int)bk, off, 64));
        uint_t bks = __builtin_amdgcn_readfirstlane(bk);
        if (lane == 0) nbr[r * KTOT + sel] = base + (int)(bks & 0x7FFu);
        int grp = (int)((bks & 0x7FFu) >> 8);
#pragma unroll
        for (int jj = 0; jj < 8; jj++)
            if (grp == jj) {
#pragma unroll
                for (int t = 0; t < 4; t++)
                    v[jj * 4 + t] = (v[jj * 4 + t] == bks) ? 0xFFFFFFFFu : v[jj * 4 + t];
                g[jj] = min(min(v[jj * 4], v[jj * 4 + 1]), min(v[jj * 4 + 2], v[jj * 4 + 3]));
            }
        lv = g[0];
#pragma unroll
        for (int j = 1; j < 8; j++) lv = min(lv, g[j]);
    }
    if (lane == 0) nbr[r * KTOT + KNN] = r;
}

// ---------------- GAT source/target scores ----------------
__global__ void k_scores(const float* __restrict__ xh, int F,
                         const float* __restrict__ a_src,
                         const float* __restrict__ a_dst,
                         float* __restrict__ s, float* __restrict__ t) {
    int g = blockIdx.x * blockDim.x + threadIdx.x;
    if (g >= NPTS * HEADS) return;
    int n = g / HEADS, h = g % HEADS;
    const float* xr = xh + (size_t)n * (HEADS * F) + h * F;
    float ss = 0.f, tt = 0.f;
    for (int f = 0; f < F; f++) {
        float v = xr[f];
        ss += v * a_src[h * F + f];
        tt += v * a_dst[h * F + f];
    }
    s[g] = ss;
    t[g] = tt;
}

// ---------------- GAT edge-softmax + aggregate (fp32 out or bf16-hi out) ----------------
// XCD-aware block swizzle: cloud = bid & 3 keeps each cloud's xh slab in 2 XCD L2s.
__global__ void k_gat(const float* __restrict__ xh, int F,
                      const float* __restrict__ s, const float* __restrict__ t,
                      const int* __restrict__ nbr,
                      const float* __restrict__ bias,
                      float* __restrict__ outf, ushort_t* __restrict__ oh) {
    int HF = HEADS * F;
    __shared__ int srcs[KTOT];
    __shared__ float alpha[KTOT * HEADS];
    int i = (blockIdx.x & 3) * PP + (blockIdx.x >> 2);
    int tid = threadIdx.x;
    if (tid < KTOT) srcs[tid] = nbr[i * KTOT + tid];
    __syncthreads();
    if (tid < KTOT * HEADS) {
        int k = tid / HEADS, h = tid % HEADS;
        float e = s[srcs[k] * HEADS + h] + t[i * HEADS + h];
        if (e < 0.f) e *= 0.2f;
        alpha[tid] = e;
    }
    __syncthreads();
    if (tid < HEADS) {
        int h = tid;
        float m = -3e38f;
        for (int k = 0; k < KTOT; k++) m = fmaxf(m, alpha[k * HEADS + h]);
        float sum = 0.f;
        for (int k = 0; k < KTOT; k++) {
            float ex = expf(alpha[k * HEADS + h] - m);
            alpha[k * HEADS + h] = ex;
            sum += ex;
        }
        float inv = 1.f / sum;
        for (int k = 0; k < KTOT; k++) alpha[k * HEADS + h] *= inv;
    }
    __syncthreads();
    int h = tid / F;
    float acc = 0.f;
    for (int k = 0; k < KTOT; k++)
        acc += alpha[k * HEADS + h] * xh[(size_t)srcs[k] * HF + tid];
    float v = acc + bias[tid];
    if (oh) oh[(size_t)i * HF + tid] = f2bs(v);
    else outf[(size_t)i * HF + tid] = v;
}

// ---------------- global max pool over rows of h[N,1024] ----------------
__global__ void k_maxpart(const float* __restrict__ h, float* __restrict__ gpart) {
    int c = blockIdx.x * 256 + threadIdx.x;
    int r0 = blockIdx.y * 256;
    float m = -3e38f;
    for (int r = r0; r < r0 + 256; r++) m = fmaxf(m, h[(size_t)r * 1024 + c]);
    gpart[blockIdx.y * 1024 + c] = m;
}

// ---------------- gproj: fused final max + split-K matmul ----------------
// block kb reduces its 128-col slice of gpart (32 parts) then accumulates its
// K-slice of g @ mw1[326:,:]; fp32 atomicAdd into zeroed gproj (+mb1 on kb 0).
__global__ void k_gproj(const float* __restrict__ gpart,
                        const float* __restrict__ mw1,
                        const float* __restrict__ mb1,
                        float* __restrict__ gproj) {
    __shared__ float gs[128];
    int kb = blockIdx.x;           // 8 blocks x 128 k
    int t = threadIdx.x;           // 256
    if (t < 128) {
        float m = -3e38f;
        for (int p = 0; p < 32; p++) m = fmaxf(m, gpart[p * 1024 + kb * 128 + t]);
        gs[t] = m;
    }
    __syncthreads();
    float acc = (kb == 0) ? mb1[t] : 0.f;
    for (int k = 0; k < 128; k++)
        acc += gs[k] * mw1[(size_t)(326 + kb * 128 + k) * 256 + t];
    atomicAdd(&gproj[t], acc);
}

// ---------------- host side ----------------
struct WT { ushort_t *h, *l; int kp; };

extern "C" void kernel_launch(void* const* d_in, const int* in_sizes, int n_in,
                              void* d_out, int out_size, void* d_ws, size_t ws_size,
                              hipStream_t stream) {
    (void)in_sizes; (void)n_in; (void)out_size; (void)ws_size;
    const float* x    = (const float*)d_in[0];
    const float* pos  = (const float*)d_in[1];
    const float* w1   = (const float*)d_in[3];
    const float* as1  = (const float*)d_in[4];
    const float* ad1  = (const float*)d_in[5];
    const float* b1   = (const float*)d_in[6];
    const float* ml1w = (const float*)d_in[7];
    const float* ml1b = (const float*)d_in[8];
    const float* w2   = (const float*)d_in[9];
    const float* as2  = (const float*)d_in[10];
    const float* ad2  = (const float*)d_in[11];
    const float* b2   = (const float*)d_in[12];
    const float* ml2w = (const float*)d_in[13];
    const float* ml2b = (const float*)d_in[14];
    const float* w3   = (const float*)d_in[15];
    const float* as3  = (const float*)d_in[16];
    const float* ad3  = (const float*)d_in[17];
    const float* b3   = (const float*)d_in[18];
    const float* ml3w = (const float*)d_in[19];
    const float* ml3b = (const float*)d_in[20];
    const float* w4   = (const float*)d_in[21];
    const float* as4  = (const float*)d_in[22];
    const float* ad4  = (const float*)d_in[23];
    const float* b4   = (const float*)d_in[24];
    const float* ml4w = (const float*)d_in[25];
    const float* ml4b = (const float*)d_in[26];
    const float* few1 = (const float*)d_in[27];
    const float* feb1 = (const float*)d_in[28];
    const float* few2 = (const float*)d_in[29];
    const float* feb2 = (const float*)d_in[30];
    const float* mw1  = (const float*)d_in[31];
    const float* mb1  = (const float*)d_in[32];
    const float* mw2  = (const float*)d_in[33];
    const float* mb2  = (const float*)d_in[34];
    const float* mw3  = (const float*)d_in[35];
    const float* mb3  = (const float*)d_in[36];
    const float* mw4  = (const float*)d_in[37];
    const float* mb4  = (const float*)d_in[38];

    float* Wb = (float*)d_ws;
    size_t off = 0;
    auto alloc = [&](size_t n) { float* p = Wb + off; off += (n + 63) & ~(size_t)63; return p; };

    float*    dist = alloc((size_t)NPTS * PP);                  // 67 MB aliased region
    ushort_t* l4h  = (ushort_t*)alloc((size_t)NPTS * LDH / 2);
    ushort_t* l4l  = (ushort_t*)alloc((size_t)NPTS * LDH / 2);
    float*    gof  = alloc((size_t)NPTS * 384);                 // gat fp32 out (12.6MB)
    ushort_t* goh  = (ushort_t*)alloc((size_t)NPTS * 384 / 2);  // stage-4 gat bf16 out
    float* sbuf  = alloc((size_t)NPTS * HEADS);
    float* tbuf  = alloc((size_t)NPTS * HEADS);
    float* sq    = alloc(NPTS);
    float* gpart = alloc(32 * 1024);
    float* gproj = alloc(256);
    int*   nbr   = (int*)alloc((size_t)NPTS * KTOT);
    ushort_t* wtpool = (ushort_t*)alloc(1831168 + 128);

    // aliases inside dist region (disjoint lifetimes)
    char* d0 = (char*)dist;
    uint_t*   dkey = (uint_t*)dist;                             // packed knn keys
    float*    xh   = dist;                                      // stages 1-4 (<=12.6MB)
    ushort_t* hah  = (ushort_t*)d0;                             // fe1 out hi (16.8MB)
    float*    h_b  = (float*)(d0 + (size_t)NPTS * 1024 * 2);    // fe2 out fp32 (33.5MB)
    ushort_t* bBh  = (ushort_t*)d0;                             // mw2 out hi (after fe2/maxpart)
    ushort_t* bAh = (ushort_t*)gof;                             // mw1 out hi (gof dead after ml4)
    ushort_t* bCh = (ushort_t*)gof;                             // mw3 out hi (bAh dead)

    // ---- zero link4 planes + gproj accumulator ----
    hipMemsetAsync(l4h, 0, (size_t)NPTS * LDH * 4, stream);
    hipMemsetAsync(gproj, 0, 256 * 4, stream);

    // ---- fused weight transpose+split (MFMA weights only) ----
    WArgs wa;
    WT wt[NSEG];
    {
        const float* srcs[NSEG] = {w2, w3, w4, ml4w, few1, few2, mw1, mw2, mw3, mw4};
        int Ks[NSEG] = {70, 134, 198, 384, 326, 1024, 326, 256, 256, 128};
        int Ns[NSEG] = {192, 192, 384, 128, 1024, 1024, 256, 256, 128, 50};
        size_t wo = 0; int tiles = 0;
        for (int i = 0; i < NSEG; i++) {
            int kp = (Ks[i] + 31) & ~31;
            wa.src[i] = srcs[i];
            wa.dst[i] = wtpool + wo;
            wa.K[i] = Ks[i]; wa.N[i] = Ns[i]; wa.Kp[i] = kp;
            wa.t0[i] = tiles;
            wt[i] = { wtpool + wo, wtpool + wo + (size_t)kp * Ns[i], kp };
            wo += (size_t)2 * kp * Ns[i];
            tiles += (kp / 32) * ((Ns[i] + 31) / 32);
        }
        k_wsplit_all<<<tiles, 256, 0, stream>>>(wa);
    }
    WT tw2 = wt[0], tw3 = wt[1], tw4 = wt[2], tml4 = wt[3], tfe1 = wt[4], tfe2 = wt[5],
       tmw1 = wt[6], tmw2 = wt[7], tmw3 = wt[8], tmw4 = wt[9];

    auto mg3 = [&](const ushort_t* Ah, const ushort_t* Al, int lda, WT t,
                   float* Cf, int ldc, int Nd, int K) {
        dim3 g((Nd + 63) / 64, NPTS / 64);
        k_mgemm3<<<g, 256, 0, stream>>>(Ah, Al, lda, t.h, t.l, t.kp, Cf, ldc, Nd, K);
    };
    auto mg1 = [&](int MT, int NT, const ushort_t* Ah, int lda, WT t,
                   float* Cf, int ldc, ushort_t* Ch, int ldhh,
                   int Nd, int K, const float* bb1, const float* bb2, int relu, int lsm) {
        dim3 g(NPTS / MT, (Nd + NT - 1) / NT);
        if (MT == 128 && NT == 64)
            k_mgemm1<128, 64><<<g, 256, 0, stream>>>(Ah, lda, t.h, t.kp, Cf, ldc, Ch, ldhh, Nd, K, bb1, bb2, relu, lsm);
        else
            k_mgemm1<64, 64><<<g, 256, 0, stream>>>(Ah, lda, t.h, t.kp, Cf, ldc, Ch, ldhh, Nd, K, bb1, bb2, relu, lsm);
    };

    dim3 dgrid(PP / 64, PP / 128, 4);
    k_build_x0<<<(NPTS * 6 + 255) / 256, 256, 0, stream>>>(x, pos, l4h, l4l);

    // ---- stage 1: fused KNN on x0 (C=6, exact fp32), GAT1 (exact fp32 path -> x1) ----
    k_knn6<<<NPTS / 4, 256, 0, stream>>>(x, pos, nbr);
    k_tw1<<<(NPTS * 192 + 255) / 256, 256, 0, stream>>>(x, pos, w1, xh);
    k_scores<<<(NPTS * HEADS + 255) / 256, 256, 0, stream>>>(xh, 64, as1, ad1, sbuf, tbuf);
    k_gat<<<NPTS, 192, 0, stream>>>(xh, 64, sbuf, tbuf, nbr, b1, gof, nullptr);
    k_vgemm<64, 4><<<NPTS / 4, 256, 0, stream>>>(gof, 192, 192, ml1w, ml1b,
        l4h + 6, l4l + 6, LDH, nullptr, 0, 0);

    // ---- stage 2: knn on x1 (C=64), GAT2 (fp32 path -> x2) ----
    k_sqnorm<<<NPTS / 256, 256, 0, stream>>>(l4h, l4l, 6, 64, sq);
    k_mdist<<<dgrid, 256, 0, stream>>>(l4h, l4l, 6, 64, sq, dkey);
    k_topk<<<NPTS / 4, 256, 0, stream>>>(dkey, nbr);
    mg3(l4h, l4l, LDH, tw2, xh, 192, 192, 70);
    k_scores<<<(NPTS * HEADS + 255) / 256, 256, 0, stream>>>(xh, 64, as2, ad2, sbuf, tbuf);
    k_gat<<<NPTS, 192, 0, stream>>>(xh, 64, sbuf, tbuf, nbr, b2, gof, nullptr);
    k_vgemm<64, 4><<<NPTS / 4, 256, 0, stream>>>(gof, 192, 192, ml2w, ml2b,
        l4h + 70, l4l + 70, LDH, nullptr, 0, 0);

    // ---- stage 3: knn on x2 (C=64), GAT3 (bf16 tier -> x3) ----
    k_sqnorm<<<NPTS / 256, 256, 0, stream>>>(l4h, l4l, 70, 64, sq);
    k_mdist<<<dgrid, 256, 0, stream>>>(l4h, l4l, 70, 64, sq, dkey);
    k_topk<<<NPTS / 4, 256, 0, stream>>>(dkey, nbr);
    mg1(64, 64, l4h, LDH, tw3, xh, 192, nullptr, 0, 192, 134, nullptr, nullptr, 0, 0);
    k_scores<<<(NPTS * HEADS + 255) / 256, 256, 0, stream>>>(xh, 64, as3, ad3, sbuf, tbuf);
    k_gat<<<NPTS, 192, 0, stream>>>(xh, 64, sbuf, tbuf, nbr, b3, gof, nullptr);
    k_vgemm<64, 4><<<NPTS / 4, 256, 0, stream>>>(gof, 192, 192, ml3w, ml3b,
        l4h + 134, nullptr, LDH, nullptr, 0, 0);

    // ---- stage 4: GAT4 reuses stage-3 nbr (bf16 tier -> x4, MFMA ml4) ----
    mg1(64, 64, l4h, LDH, tw4, xh, 384, nullptr, 0, 384, 198, nullptr, nullptr, 0, 0);
    k_scores<<<(NPTS * HEADS + 255) / 256, 256, 0, stream>>>(xh, 128, as4, ad4, sbuf, tbuf);
    k_gat<<<NPTS, 384, 0, stream>>>(xh, 128, sbuf, tbuf, nbr, b4, nullptr, goh);
    mg1(64, 64, goh, 384, tml4, nullptr, 0, l4h + 198, LDH, 128, 384, ml4b, nullptr, 0, 0);

    // ---- fe_mlp + global max (bf16 tier, 128x64 tiles -> 1024 blocks) ----
    mg1(128, 64, l4h, LDH, tfe1, nullptr, 0, hah, 1024, 1024, 326, feb1, nullptr, 1, 0);
    mg1(128, 64, hah, 1024, tfe2, h_b, 1024, nullptr, 0, 1024, 1024, feb2, nullptr, 0, 0);
    k_maxpart<<<dim3(4, 32), 256, 0, stream>>>(h_b, gpart);
    k_gproj<<<8, 256, 0, stream>>>(gpart, mw1, mb1, gproj);

    // ---- head (bf16 tier; mw4 fuses log_softmax and writes d_out) ----
    mg1(128, 64, l4h, LDH, tmw1, nullptr, 0, bAh, 256, 256, 326, nullptr, gproj, 1, 0);
    mg1(128, 64, bAh, 256, tmw2, nullptr, 0, bBh, 256, 256, 256, mb2, nullptr, 1, 0);
    mg1(64, 64, bBh, 256, tmw3, nullptr, 0, bCh, 128, 128, 256, mb3, nullptr, 1, 0);
    mg1(64, 64, bCh, 128, tmw4, (float*)d_out, 50, nullptr, 0, 50, 128, mb4, nullptr, 0, 1);
}

// Round 14
// 757.821 us; speedup vs baseline: 1.0513x; 1.0513x over previous
//
#include <hip/hip_runtime.h>
#include <hip/hip_bf16.h>
#include <hip/amd_detail/amd_hip_vector_types.h>

#define NPTS 8192
#define PP 2048
#define KNN 30
#define KTOT 31
#define HEADS 3
#define LDH 352   // padded ld for link4 hi/lo (bf16): >= Kpad32(326), mult of 8
#define NSEG 10

typedef __attribute__((ext_vector_type(8))) short short8;
typedef __attribute__((ext_vector_type(4))) float floatx4;
typedef __attribute__((ext_vector_type(4))) unsigned int uint4_t;
typedef unsigned short ushort_t;
typedef unsigned int uint_t;

__device__ inline ushort_t f2bs(float v) {
    __hip_bfloat16 b = __float2bfloat16(v);
    return *reinterpret_cast<ushort_t*>(&b);
}
__device__ inline float bs2f(ushort_t u) {
    __hip_bfloat16 b = *reinterpret_cast<__hip_bfloat16*>(&u);
    return __bfloat162float(b);
}
__device__ inline void split2(float v, ushort_t& h, ushort_t& l) {
    h = f2bs(v);
    l = f2bs(v - bs2f(h));
}

// ---------------- build x0 (hi/lo) into link4 cols 0..5 ----------------
__global__ void k_build_x0(const float* __restrict__ x, const float* __restrict__ pos,
                           ushort_t* __restrict__ lh, ushort_t* __restrict__ ll) {
    int i = blockIdx.x * blockDim.x + threadIdx.x;
    if (i >= NPTS * 6) return;
    int n = i / 6, c = i % 6;
    float v = (c < 3) ? x[n * 3 + c] : pos[n * 3 + (c - 3)];
    ushort_t h, l; split2(v, h, l);
    lh[(size_t)n * LDH + c] = h;
    ll[(size_t)n * LDH + c] = l;
}

// ---------------- per-row squared norms from hi/lo ----------------
__global__ void k_sqnorm(const ushort_t* __restrict__ lh, const ushort_t* __restrict__ ll,
                         int co, int C, float* __restrict__ sq) {
    int n = blockIdx.x * blockDim.x + threadIdx.x;
    if (n >= NPTS) return;
    const ushort_t* ph = lh + (size_t)n * LDH + co;
    const ushort_t* pl = ll + (size_t)n * LDH + co;
    float s = 0.f;
    for (int c = 0; c < C; c++) { float v = bs2f(ph[c]) + bs2f(pl[c]); s += v * v; }
    sq[n] = s;
}

// ---------------- fused weight transpose + split (10 MFMA weights, one launch) ----------
struct WArgs {
    const float* src[NSEG];
    ushort_t* dst[NSEG];
    int K[NSEG], N[NSEG], Kp[NSEG], t0[NSEG];
};
__global__ void k_wsplit_all(WArgs a) {
    int bt = blockIdx.x;
    int si = 0;
#pragma unroll
    for (int i = 1; i < NSEG; i++) if (bt >= a.t0[i]) si = i;
    int t = bt - a.t0[si];
    int K_ = a.K[si], N_ = a.N[si], Kp = a.Kp[si];
    const float* src = a.src[si];
    ushort_t* dh = a.dst[si];
    ushort_t* dl = dh + (size_t)Kp * N_;
    int tX = (N_ + 31) >> 5;
    int k0 = (t / tX) * 32, n0 = (t % tX) * 32;
    __shared__ float tt[32][33];
    int c = threadIdx.x & 31, r8 = threadIdx.x >> 5;
#pragma unroll
    for (int i = 0; i < 4; i++) {
        int r = r8 + i * 8;
        int k = k0 + r, n = n0 + c;
        tt[r][c] = (k < K_ && n < N_) ? src[(size_t)k * N_ + n] : 0.f;
    }
    __syncthreads();
#pragma unroll
    for (int i = 0; i < 4; i++) {
        int r = r8 + i * 8;
        int n = n0 + r, k = k0 + c;
        if (n < N_) {
            float v = tt[c][r];
            ushort_t h, l; split2(v, h, l);
            dh[(size_t)n * Kp + k] = h;
            dl[(size_t)n * Kp + k] = l;
        }
    }
}

// -------- pure-bf16 MFMA GEMM, software-pipelined; optional fused log_softmax ------
template<int MT, int NT>
__global__ __launch_bounds__(256)
void k_mgemm1(const ushort_t* __restrict__ A, int lda,
              const ushort_t* __restrict__ W, int ldw,
              float* __restrict__ Cf, int ldc,
              ushort_t* __restrict__ Ch, int ldh,
              int Ndim, int K,
              const float* __restrict__ bias1, const float* __restrict__ bias2,
              int relu, int lsm) {
    constexpr int MTW = MT / 64;
    constexpr int NTT = NT / 16;
    __shared__ ushort_t As[2][MT * 40];
    __shared__ ushort_t Bs[2][NT * 40];
    int tid = threadIdx.x;
    int w = tid >> 6, lane = tid & 63;
    int quad = lane >> 4, l16 = lane & 15;
    int m0 = blockIdx.x * MT, n0 = blockIdx.y * NT;
    uint4_t pa[MT / 64], pb[NT / 64];
    auto prefetch = [&](int k0) {
#pragma unroll
        for (int rep = 0; rep < MT / 64; rep++) {
            int idx = tid + rep * 256;
            int row = idx >> 2, q = idx & 3;
            pa[rep] = *(const uint4_t*)(A + (size_t)(m0 + row) * lda + k0 + q * 8);
        }
#pragma unroll
        for (int rep = 0; rep < NT / 64; rep++) {
            int idx = tid + rep * 256;
            int row = idx >> 2, q = idx & 3;
            uint4_t v = {0, 0, 0, 0};
            if (n0 + row < Ndim) v = *(const uint4_t*)(W + (size_t)(n0 + row) * ldw + k0 + q * 8);
            pb[rep] = v;
        }
    };
    auto stage = [&](int buf) {
#pragma unroll
        for (int rep = 0; rep < MT / 64; rep++) {
            int idx = tid + rep * 256;
            int row = idx >> 2, q = idx & 3;
            *(uint4_t*)&As[buf][row * 40 + q * 8] = pa[rep];
        }
#pragma unroll
        for (int rep = 0; rep < NT / 64; rep++) {
            int idx = tid + rep * 256;
            int row = idx >> 2, q = idx & 3;
            *(uint4_t*)&Bs[buf][row * 40 + q * 8] = pb[rep];
        }
    };
    floatx4 acc[MTW][NTT] = {};
    prefetch(0);
    stage(0);
    __syncthreads();
    int cur = 0;
    for (int k0 = 0; k0 < K; k0 += 32) {
        bool more = (k0 + 32 < K);
        if (more) prefetch(k0 + 32);
        short8 ah[MTW];
#pragma unroll
        for (int mt = 0; mt < MTW; mt++) {
            int r = w * (MT / 4) + mt * 16 + l16;
            ah[mt] = *(short8*)&As[cur][r * 40 + quad * 8];
        }
#pragma unroll
        for (int nt = 0; nt < NTT; nt++) {
            int r = nt * 16 + l16;
            short8 bh = *(short8*)&Bs[cur][r * 40 + quad * 8];
#pragma unroll
            for (int mt = 0; mt < MTW; mt++)
                acc[mt][nt] = __builtin_amdgcn_mfma_f32_16x16x32_bf16(ah[mt], bh, acc[mt][nt], 0, 0, 0);
        }
        if (more) stage(cur ^ 1);
        __syncthreads();
        cur ^= 1;
    }
    if (lsm) {
        // fused log_softmax over Ndim (<= NT) cols; whole row lives in this block
#pragma unroll
        for (int mt = 0; mt < MTW; mt++) {
#pragma unroll
            for (int r = 0; r < 4; r++) {
                float vv[NTT];
                float mrow = -3e38f;
#pragma unroll
                for (int nt = 0; nt < NTT; nt++) {
                    int n = n0 + nt * 16 + l16;
                    float val = (n < Ndim) ? acc[mt][nt][r] + bias1[n] : -3e38f;
                    vv[nt] = val;
                    mrow = fmaxf(mrow, val);
                }
#pragma unroll
                for (int off = 8; off >= 1; off >>= 1)
                    mrow = fmaxf(mrow, __shfl_xor(mrow, off, 64));
                float s = 0.f;
#pragma unroll
                for (int nt = 0; nt < NTT; nt++)
                    if (vv[nt] > -1e38f) s += expf(vv[nt] - mrow);
#pragma unroll
                for (int off = 8; off >= 1; off >>= 1)
                    s += __shfl_xor(s, off, 64);
                float lse = mrow + logf(s);
                int m = m0 + w * (MT / 4) + mt * 16 + quad * 4 + r;
#pragma unroll
                for (int nt = 0; nt < NTT; nt++) {
                    int n = n0 + nt * 16 + l16;
                    if (n < Ndim) Cf[(size_t)m * ldc + n] = vv[nt] - lse;
                }
            }
        }
        return;
    }
#pragma unroll
    for (int mt = 0; mt < MTW; mt++) {
#pragma unroll
        for (int nt = 0; nt < NTT; nt++) {
#pragma unroll
            for (int r = 0; r < 4; r++) {
                int m = m0 + w * (MT / 4) + mt * 16 + quad * 4 + r;
                int n = n0 + nt * 16 + l16;
                if (n < Ndim) {
                    float v = acc[mt][nt][r];
                    if (bias1) v += bias1[n];
                    if (bias2) v += bias2[n];
                    if (relu && v < 0.f) v = 0.f;
                    if (Cf) Cf[(size_t)m * ldc + n] = v;
                    if (Ch) Ch[(size_t)m * ldh + n] = f2bs(v);
                }
            }
        }
    }
}

// ---------------- split-bf16 (3-term) MFMA GEMM, single-buffered (small K only) -----
__global__ __launch_bounds__(256)
void k_mgemm3(const ushort_t* __restrict__ Ah, const ushort_t* __restrict__ Al, int lda,
              const ushort_t* __restrict__ Wh, const ushort_t* __restrict__ Wl, int ldw,
              float* __restrict__ Cf, int ldc,
              int Ndim, int K) {
    constexpr int NTT = 4;
    __shared__ ushort_t AsH[64 * 40], BsH[64 * 40], AsL[64 * 40], BsL[64 * 40];
    int tid = threadIdx.x;
    int w = tid >> 6, lane = tid & 63;
    int quad = lane >> 4, l16 = lane & 15;
    int m0 = blockIdx.y * 64, n0 = blockIdx.x * 64;
    floatx4 acc[NTT] = {};
    for (int k0 = 0; k0 < K; k0 += 32) {
        {
            int row = tid >> 2, q = tid & 3;
            size_t go = (size_t)(m0 + row) * lda + k0 + q * 8;
            *(uint4_t*)&AsH[row * 40 + q * 8] = *(const uint4_t*)(Ah + go);
            *(uint4_t*)&AsL[row * 40 + q * 8] = *(const uint4_t*)(Al + go);
            uint4_t vh = {0, 0, 0, 0}, vl = {0, 0, 0, 0};
            size_t gw = (size_t)(n0 + row) * ldw + k0 + q * 8;
            if (n0 + row < Ndim) { vh = *(const uint4_t*)(Wh + gw); vl = *(const uint4_t*)(Wl + gw); }
            *(uint4_t*)&BsH[row * 40 + q * 8] = vh;
            *(uint4_t*)&BsL[row * 40 + q * 8] = vl;
        }
        __syncthreads();
        short8 ah, al;
        {
            int r = w * 16 + l16;
            ah = *(short8*)&AsH[r * 40 + quad * 8];
            al = *(short8*)&AsL[r * 40 + quad * 8];
        }
#pragma unroll
        for (int nt = 0; nt < NTT; nt++) {
            int r = nt * 16 + l16;
            short8 bh = *(short8*)&BsH[r * 40 + quad * 8];
            short8 bl = *(short8*)&BsL[r * 40 + quad * 8];
            acc[nt] = __builtin_amdgcn_mfma_f32_16x16x32_bf16(ah, bh, acc[nt], 0, 0, 0);
            acc[nt] = __builtin_amdgcn_mfma_f32_16x16x32_bf16(ah, bl, acc[nt], 0, 0, 0);
            acc[nt] = __builtin_amdgcn_mfma_f32_16x16x32_bf16(al, bh, acc[nt], 0, 0, 0);
        }
        __syncthreads();
    }
#pragma unroll
    for (int nt = 0; nt < NTT; nt++) {
#pragma unroll
        for (int r = 0; r < 4; r++) {
            int m = m0 + w * 16 + quad * 4 + r;
            int n = n0 + nt * 16 + l16;
            if (n < Ndim) Cf[(size_t)m * ldc + n] = acc[nt][r];
        }
    }
}

// ---------------- exact-fp32 VALU GEMM for small N, K%64==0: LDS-tiled W ----------
template<int N_, int NPB>
__global__ __launch_bounds__(NPB * N_)
void k_vgemm(const float* __restrict__ A, int lda, int K_,
             const float* __restrict__ W, const float* __restrict__ bias,
             ushort_t* __restrict__ Ch, ushort_t* __restrict__ Cl, int ldh,
             float* __restrict__ Cf, int ldc, int relu) {
    constexpr int KT = 64;
    __shared__ float Ws[KT * N_];
    __shared__ float As[NPB * KT];
    int t = threadIdx.x;
    int n0 = blockIdx.x * NPB;
    int node = t / N_, j = t % N_;
    float acc = bias ? bias[j] : 0.f;
    for (int k0 = 0; k0 < K_; k0 += KT) {
        for (int idx = t; idx < KT * N_; idx += NPB * N_)
            Ws[idx] = W[(size_t)(k0 + idx / N_) * N_ + idx % N_];
        for (int idx = t; idx < NPB * KT; idx += NPB * N_)
            As[idx] = A[(size_t)(n0 + idx / KT) * lda + k0 + idx % KT];
        __syncthreads();
#pragma unroll
        for (int kk = 0; kk < KT; kk++)
            acc += As[node * KT + kk] * Ws[kk * N_ + j];
        __syncthreads();
    }
    if (relu && acc < 0.f) acc = 0.f;
    size_t m = n0 + node;
    if (Cf) Cf[m * ldc + j] = acc;
    if (Ch) {
        ushort_t h = f2bs(acc);
        Ch[m * ldh + j] = h;
        if (Cl) Cl[m * ldh + j] = f2bs(acc - bs2f(h));
    }
}

// ---------------- tw1: xh = [x|pos] @ w1, exact fp32 (K=6) ----------------
__global__ void k_tw1(const float* __restrict__ x, const float* __restrict__ pos,
                      const float* __restrict__ w1, float* __restrict__ xh) {
    int t = blockIdx.x * blockDim.x + threadIdx.x;
    if (t >= NPTS * 192) return;
    int n = t / 192, j = t % 192;
    float acc = 0.f;
#pragma unroll
    for (int c = 0; c < 3; c++) {
        acc += x[n * 3 + c] * w1[c * 192 + j];
        acc += pos[n * 3 + c] * w1[(3 + c) * 192 + j];
    }
    xh[(size_t)n * 192 + j] = acc;
}

// ---------------- split-bf16 MFMA pairwise distances -> packed sort keys ----------------
__global__ __launch_bounds__(256)
void k_mdist(const ushort_t* __restrict__ Lh, const ushort_t* __restrict__ Ll,
             int co, int C, const float* __restrict__ sq, uint_t* __restrict__ keys) {
    __shared__ ushort_t AsH[128 * 40], AsL[128 * 40], BsH[64 * 40], BsL[64 * 40];
    int tid = threadIdx.x;
    int w = tid >> 6, lane = tid & 63;
    int quad = lane >> 4, l16 = lane & 15;
    int b = blockIdx.z, cb = b * PP;
    int i0 = blockIdx.y * 128, j0 = blockIdx.x * 64;
    floatx4 acc[2][4] = {};
    for (int k0 = 0; k0 < C; k0 += 32) {
#pragma unroll
        for (int rep = 0; rep < 8; rep++) {
            int d = tid + rep * 256;
            int row = d >> 4, c2 = d & 15;
            size_t gi = ((size_t)(cb + i0 + row) * LDH + co + k0 + c2 * 2) >> 1;
            *(uint_t*)&AsH[row * 40 + c2 * 2] = ((const uint_t*)Lh)[gi];
            *(uint_t*)&AsL[row * 40 + c2 * 2] = ((const uint_t*)Ll)[gi];
        }
#pragma unroll
        for (int rep = 0; rep < 4; rep++) {
            int d = tid + rep * 256;
            int row = d >> 4, c2 = d & 15;
            size_t gi = ((size_t)(cb + j0 + row) * LDH + co + k0 + c2 * 2) >> 1;
            *(uint_t*)&BsH[row * 40 + c2 * 2] = ((const uint_t*)Lh)[gi];
            *(uint_t*)&BsL[row * 40 + c2 * 2] = ((const uint_t*)Ll)[gi];
        }
        __syncthreads();
        short8 ah[2], al[2];
#pragma unroll
        for (int mt = 0; mt < 2; mt++) {
            int r = w * 32 + mt * 16 + l16;
            ah[mt] = *(short8*)&AsH[r * 40 + quad * 8];
            al[mt] = *(short8*)&AsL[r * 40 + quad * 8];
        }
#pragma unroll
        for (int nt = 0; nt < 4; nt++) {
            int r = nt * 16 + l16;
            short8 bh = *(short8*)&BsH[r * 40 + quad * 8];
            short8 bl = *(short8*)&BsL[r * 40 + quad * 8];
#pragma unroll
            for (int mt = 0; mt < 2; mt++) {
                acc[mt][nt] = __builtin_amdgcn_mfma_f32_16x16x32_bf16(ah[mt], bh, acc[mt][nt], 0, 0, 0);
                acc[mt][nt] = __builtin_amdgcn_mfma_f32_16x16x32_bf16(ah[mt], bl, acc[mt][nt], 0, 0, 0);
                acc[mt][nt] = __builtin_amdgcn_mfma_f32_16x16x32_bf16(al[mt], bh, acc[mt][nt], 0, 0, 0);
            }
        }
        __syncthreads();
    }
#pragma unroll
    for (int mt = 0; mt < 2; mt++) {
#pragma unroll
        for (int nt = 0; nt < 4; nt++) {
#pragma unroll
            for (int r = 0; r < 4; r++) {
                int il = i0 + w * 32 + mt * 16 + quad * 4 + r;
                int jl = j0 + nt * 16 + l16;
                float dd = sq[cb + il] + sq[cb + jl] - 2.f * acc[mt][nt][r];
                dd = (il == jl) ? 3e9f : fmaxf(dd, 0.f);
                keys[(size_t)(cb + il) * PP + jl] =
                    (__float_as_uint(dd) & 0xFFFFF800u) | (uint_t)jl;
            }
        }
    }
}

// ---------------- top-30 smallest per row via packed u32 keys ----------------
__global__ __launch_bounds__(256)
void k_topk(const uint_t* __restrict__ keys, int* __restrict__ nbr) {
    int r = blockIdx.x * 4 + (threadIdx.x >> 6);
    int lane = threadIdx.x & 63;
    int base = (r / PP) * PP;
    const uint_t* row = keys + (size_t)r * PP;
    uint_t v[32];
#pragma unroll
    for (int j = 0; j < 8; j++)
        *(uint4_t*)&v[j * 4] = *(const uint4_t*)(row + lane * 4 + j * 256);
    uint_t g[8];
#pragma unroll
    for (int j = 0; j < 8; j++)
        g[j] = min(min(v[j * 4], v[j * 4 + 1]), min(v[j * 4 + 2], v[j * 4 + 3]));
    uint_t lv = g[0];
#pragma unroll
    for (int j = 1; j < 8; j++) lv = min(lv, g[j]);
    for (int sel = 0; sel < KNN; sel++) {
        uint_t bk = lv;
#pragma unroll
        for (int off = 32; off > 0; off >>= 1)
            bk = min(bk, (uint_t)__shfl_xor((int)bk, off, 64));
        uint_t bks = __builtin_amdgcn_readfirstlane(bk);
        if (lane == 0) nbr[r * KTOT + sel] = base + (int)(bks & 0x7FFu);
        int grp = (int)((bks & 0x7FFu) >> 8);
#pragma unroll
        for (int jj = 0; jj < 8; jj++)
            if (grp == jj) {
#pragma unroll
                for (int t = 0; t < 4; t++)
                    v[jj * 4 + t] = (v[jj * 4 + t] == bks) ? 0xFFFFFFFFu : v[jj * 4 + t];
                g[jj] = min(min(v[jj * 4], v[jj * 4 + 1]), min(v[jj * 4 + 2], v[jj * 4 + 3]));
            }
        lv = g[0];
#pragma unroll
        for (int j = 1; j < 8; j++) lv = min(lv, g[j]);
    }
    if (lane == 0) nbr[r * KTOT + KNN] = r;
}

// ---------------- GAT source/target scores ----------------
__global__ void k_scores(const float* __restrict__ xh, int F,
                         const float* __restrict__ a_src,
                         const float* __restrict__ a_dst,
                         float* __restrict__ s, float* __restrict__ t) {
    int g = blockIdx.x * blockDim.x + threadIdx.x;
    if (g >= NPTS * HEADS) return;
    int n = g / HEADS, h = g % HEADS;
    const float* xr = xh + (size_t)n * (HEADS * F) + h * F;
    float ss = 0.f, tt = 0.f;
    for (int f = 0; f < F; f++) {
        float v = xr[f];
        ss += v * a_src[h * F + f];
        tt += v * a_dst[h * F + f];
    }
    s[g] = ss;
    t[g] = tt;
}

// ---------------- GAT edge-softmax + aggregate (fp32 out or bf16-hi out) ----------------
// XCD-aware block swizzle: cloud = bid & 3 keeps each cloud's xh slab in 2 XCD L2s.
__global__ void k_gat(const float* __restrict__ xh, int F,
                      const float* __restrict__ s, const float* __restrict__ t,
                      const int* __restrict__ nbr,
                      const float* __restrict__ bias,
                      float* __restrict__ outf, ushort_t* __restrict__ oh) {
    int HF = HEADS * F;
    __shared__ int srcs[KTOT];
    __shared__ float alpha[KTOT * HEADS];
    int i = (blockIdx.x & 3) * PP + (blockIdx.x >> 2);
    int tid = threadIdx.x;
    if (tid < KTOT) srcs[tid] = nbr[i * KTOT + tid];
    __syncthreads();
    if (tid < KTOT * HEADS) {
        int k = tid / HEADS, h = tid % HEADS;
        float e = s[srcs[k] * HEADS + h] + t[i * HEADS + h];
        if (e < 0.f) e *= 0.2f;
        alpha[tid] = e;
    }
    __syncthreads();
    if (tid < HEADS) {
        int h = tid;
        float m = -3e38f;
        for (int k = 0; k < KTOT; k++) m = fmaxf(m, alpha[k * HEADS + h]);
        float sum = 0.f;
        for (int k = 0; k < KTOT; k++) {
            float ex = expf(alpha[k * HEADS + h] - m);
            alpha[k * HEADS + h] = ex;
            sum += ex;
        }
        float inv = 1.f / sum;
        for (int k = 0; k < KTOT; k++) alpha[k * HEADS + h] *= inv;
    }
    __syncthreads();
    int h = tid / F;
    float acc = 0.f;
    for (int k = 0; k < KTOT; k++)
        acc += alpha[k * HEADS + h] * xh[(size_t)srcs[k] * HF + tid];
    float v = acc + bias[tid];
    if (oh) oh[(size_t)i * HF + tid] = f2bs(v);
    else outf[(size_t)i * HF + tid] = v;
}

// ---------------- global max pool over rows of h[N,1024] ----------------
__global__ void k_maxpart(const float* __restrict__ h, float* __restrict__ gpart) {
    int c = blockIdx.x * 256 + threadIdx.x;
    int r0 = blockIdx.y * 256;
    float m = -3e38f;
    for (int r = r0; r < r0 + 256; r++) m = fmaxf(m, h[(size_t)r * 1024 + c]);
    gpart[blockIdx.y * 1024 + c] = m;
}

// ---------------- gproj: fused final max + split-K matmul ----------------
__global__ void k_gproj(const float* __restrict__ gpart,
                        const float* __restrict__ mw1,
                        const float* __restrict__ mb1,
                        float* __restrict__ gproj) {
    __shared__ float gs[128];
    int kb = blockIdx.x;           // 8 blocks x 128 k
    int t = threadIdx.x;           // 256
    if (t < 128) {
        float m = -3e38f;
        for (int p = 0; p < 32; p++) m = fmaxf(m, gpart[p * 1024 + kb * 128 + t]);
        gs[t] = m;
    }
    __syncthreads();
    float acc = (kb == 0) ? mb1[t] : 0.f;
    for (int k = 0; k < 128; k++)
        acc += gs[k] * mw1[(size_t)(326 + kb * 128 + k) * 256 + t];
    atomicAdd(&gproj[t], acc);
}

// ---------------- host side ----------------
struct WT { ushort_t *h, *l; int kp; };

extern "C" void kernel_launch(void* const* d_in, const int* in_sizes, int n_in,
                              void* d_out, int out_size, void* d_ws, size_t ws_size,
                              hipStream_t stream) {
    (void)in_sizes; (void)n_in; (void)out_size; (void)ws_size;
    const float* x    = (const float*)d_in[0];
    const float* pos  = (const float*)d_in[1];
    const float* w1   = (const float*)d_in[3];
    const float* as1  = (const float*)d_in[4];
    const float* ad1  = (const float*)d_in[5];
    const float* b1   = (const float*)d_in[6];
    const float* ml1w = (const float*)d_in[7];
    const float* ml1b = (const float*)d_in[8];
    const float* w2   = (const float*)d_in[9];
    const float* as2  = (const float*)d_in[10];
    const float* ad2  = (const float*)d_in[11];
    const float* b2   = (const float*)d_in[12];
    const float* ml2w = (const float*)d_in[13];
    const float* ml2b = (const float*)d_in[14];
    const float* w3   = (const float*)d_in[15];
    const float* as3  = (const float*)d_in[16];
    const float* ad3  = (const float*)d_in[17];
    const float* b3   = (const float*)d_in[18];
    const float* ml3w = (const float*)d_in[19];
    const float* ml3b = (const float*)d_in[20];
    const float* w4   = (const float*)d_in[21];
    const float* as4  = (const float*)d_in[22];
    const float* ad4  = (const float*)d_in[23];
    const float* b4   = (const float*)d_in[24];
    const float* ml4w = (const float*)d_in[25];
    const float* ml4b = (const float*)d_in[26];
    const float* few1 = (const float*)d_in[27];
    const float* feb1 = (const float*)d_in[28];
    const float* few2 = (const float*)d_in[29];
    const float* feb2 = (const float*)d_in[30];
    const float* mw1  = (const float*)d_in[31];
    const float* mb1  = (const float*)d_in[32];
    const float* mw2  = (const float*)d_in[33];
    const float* mb2  = (const float*)d_in[34];
    const float* mw3  = (const float*)d_in[35];
    const float* mb3  = (const float*)d_in[36];
    const float* mw4  = (const float*)d_in[37];
    const float* mb4  = (const float*)d_in[38];

    float* Wb = (float*)d_ws;
    size_t off = 0;
    auto alloc = [&](size_t n) { float* p = Wb + off; off += (n + 63) & ~(size_t)63; return p; };

    float*    dist = alloc((size_t)NPTS * PP);                  // 67 MB aliased region
    ushort_t* l4h  = (ushort_t*)alloc((size_t)NPTS * LDH / 2);
    ushort_t* l4l  = (ushort_t*)alloc((size_t)NPTS * LDH / 2);
    float*    gof  = alloc((size_t)NPTS * 384);                 // gat fp32 out (12.6MB)
    ushort_t* goh  = (ushort_t*)alloc((size_t)NPTS * 384 / 2);  // stage-4 gat bf16 out
    float* sbuf  = alloc((size_t)NPTS * HEADS);
    float* tbuf  = alloc((size_t)NPTS * HEADS);
    float* sq    = alloc(NPTS);
    float* gpart = alloc(32 * 1024);
    float* gproj = alloc(256);
    int*   nbr   = (int*)alloc((size_t)NPTS * KTOT);
    ushort_t* wtpool = (ushort_t*)alloc(1831168 + 128);

    // aliases inside dist region (disjoint lifetimes)
    char* d0 = (char*)dist;
    uint_t*   dkey = (uint_t*)dist;                             // packed knn keys
    float*    xh   = dist;                                      // stages 1-4 (<=12.6MB)
    ushort_t* hah  = (ushort_t*)d0;                             // fe1 out hi (16.8MB)
    float*    h_b  = (float*)(d0 + (size_t)NPTS * 1024 * 2);    // fe2 out fp32 (33.5MB)
    ushort_t* bBh  = (ushort_t*)d0;                             // mw2 out hi (after fe2/maxpart)
    ushort_t* bAh = (ushort_t*)gof;                             // mw1 out hi (gof dead after ml4)
    ushort_t* bCh = (ushort_t*)gof;                             // mw3 out hi (bAh dead)

    // ---- zero link4 planes + gproj accumulator ----
    hipMemsetAsync(l4h, 0, (size_t)NPTS * LDH * 4, stream);
    hipMemsetAsync(gproj, 0, 256 * 4, stream);

    // ---- fused weight transpose+split (MFMA weights only) ----
    WArgs wa;
    WT wt[NSEG];
    {
        const float* srcs[NSEG] = {w2, w3, w4, ml4w, few1, few2, mw1, mw2, mw3, mw4};
        int Ks[NSEG] = {70, 134, 198, 384, 326, 1024, 326, 256, 256, 128};
        int Ns[NSEG] = {192, 192, 384, 128, 1024, 1024, 256, 256, 128, 50};
        size_t wo = 0; int tiles = 0;
        for (int i = 0; i < NSEG; i++) {
            int kp = (Ks[i] + 31) & ~31;
            wa.src[i] = srcs[i];
            wa.dst[i] = wtpool + wo;
            wa.K[i] = Ks[i]; wa.N[i] = Ns[i]; wa.Kp[i] = kp;
            wa.t0[i] = tiles;
            wt[i] = { wtpool + wo, wtpool + wo + (size_t)kp * Ns[i], kp };
            wo += (size_t)2 * kp * Ns[i];
            tiles += (kp / 32) * ((Ns[i] + 31) / 32);
        }
        k_wsplit_all<<<tiles, 256, 0, stream>>>(wa);
    }
    WT tw2 = wt[0], tw3 = wt[1], tw4 = wt[2], tml4 = wt[3], tfe1 = wt[4], tfe2 = wt[5],
       tmw1 = wt[6], tmw2 = wt[7], tmw3 = wt[8], tmw4 = wt[9];

    auto mg3 = [&](const ushort_t* Ah, const ushort_t* Al, int lda, WT t,
                   float* Cf, int ldc, int Nd, int K) {
        dim3 g((Nd + 63) / 64, NPTS / 64);
        k_mgemm3<<<g, 256, 0, stream>>>(Ah, Al, lda, t.h, t.l, t.kp, Cf, ldc, Nd, K);
    };
    auto mg1 = [&](int MT, int NT, const ushort_t* Ah, int lda, WT t,
                   float* Cf, int ldc, ushort_t* Ch, int ldhh,
                   int Nd, int K, const float* bb1, const float* bb2, int relu, int lsm) {
        dim3 g(NPTS / MT, (Nd + NT - 1) / NT);
        if (MT == 128 && NT == 64)
            k_mgemm1<128, 64><<<g, 256, 0, stream>>>(Ah, lda, t.h, t.kp, Cf, ldc, Ch, ldhh, Nd, K, bb1, bb2, relu, lsm);
        else
            k_mgemm1<64, 64><<<g, 256, 0, stream>>>(Ah, lda, t.h, t.kp, Cf, ldc, Ch, ldhh, Nd, K, bb1, bb2, relu, lsm);
    };

    dim3 dgrid(PP / 64, PP / 128, 4);
    k_build_x0<<<(NPTS * 6 + 255) / 256, 256, 0, stream>>>(x, pos, l4h, l4l);

    // ---- stage 1: knn on x0 (C=6), GAT1 (exact fp32 path -> x1) ----
    k_sqnorm<<<NPTS / 256, 256, 0, stream>>>(l4h, l4l, 0, 6, sq);
    k_mdist<<<dgrid, 256, 0, stream>>>(l4h, l4l, 0, 6, sq, dkey);
    k_topk<<<NPTS / 4, 256, 0, stream>>>(dkey, nbr);
    k_tw1<<<(NPTS * 192 + 255) / 256, 256, 0, stream>>>(x, pos, w1, xh);
    k_scores<<<(NPTS * HEADS + 255) / 256, 256, 0, stream>>>(xh, 64, as1, ad1, sbuf, tbuf);
    k_gat<<<NPTS, 192, 0, stream>>>(xh, 64, sbuf, tbuf, nbr, b1, gof, nullptr);
    k_vgemm<64, 4><<<NPTS / 4, 256, 0, stream>>>(gof, 192, 192, ml1w, ml1b,
        l4h + 6, l4l + 6, LDH, nullptr, 0, 0);

    // ---- stage 2: knn on x1 (C=64), GAT2 (fp32 path -> x2) ----
    k_sqnorm<<<NPTS / 256, 256, 0, stream>>>(l4h, l4l, 6, 64, sq);
    k_mdist<<<dgrid, 256, 0, stream>>>(l4h, l4l, 6, 64, sq, dkey);
    k_topk<<<NPTS / 4, 256, 0, stream>>>(dkey, nbr);
    mg3(l4h, l4l, LDH, tw2, xh, 192, 192, 70);
    k_scores<<<(NPTS * HEADS + 255) / 256, 256, 0, stream>>>(xh, 64, as2, ad2, sbuf, tbuf);
    k_gat<<<NPTS, 192, 0, stream>>>(xh, 64, sbuf, tbuf, nbr, b2, gof, nullptr);
    k_vgemm<64, 4><<<NPTS / 4, 256, 0, stream>>>(gof, 192, 192, ml2w, ml2b,
        l4h + 70, l4l + 70, LDH, nullptr, 0, 0);

    // ---- stage 3: knn on x2 (C=64), GAT3 (bf16 tier -> x3) ----
    k_sqnorm<<<NPTS / 256, 256, 0, stream>>>(l4h, l4l, 70, 64, sq);
    k_mdist<<<dgrid, 256, 0, stream>>>(l4h, l4l, 70, 64, sq, dkey);
    k_topk<<<NPTS / 4, 256, 0, stream>>>(dkey, nbr);
    mg1(64, 64, l4h, LDH, tw3, xh, 192, nullptr, 0, 192, 134, nullptr, nullptr, 0, 0);
    k_scores<<<(NPTS * HEADS + 255) / 256, 256, 0, stream>>>(xh, 64, as3, ad3, sbuf, tbuf);
    k_gat<<<NPTS, 192, 0, stream>>>(xh, 64, sbuf, tbuf, nbr, b3, gof, nullptr);
    k_vgemm<64, 4><<<NPTS / 4, 256, 0, stream>>>(gof, 192, 192, ml3w, ml3b,
        l4h + 134, nullptr, LDH, nullptr, 0, 0);

    // ---- stage 4: GAT4 reuses stage-3 nbr (bf16 tier -> x4, MFMA ml4) ----
    mg1(64, 64, l4h, LDH, tw4, xh, 384, nullptr, 0, 384, 198, nullptr, nullptr, 0, 0);
    k_scores<<<(NPTS * HEADS + 255) / 256, 256, 0, stream>>>(xh, 128, as4, ad4, sbuf, tbuf);
    k_gat<<<NPTS, 384, 0, stream>>>(xh, 128, sbuf, tbuf, nbr, b4, nullptr, goh);
    mg1(64, 64, goh, 384, tml4, nullptr, 0, l4h + 198, LDH, 128, 384, ml4b, nullptr, 0, 0);

    // ---- fe_mlp + global max (bf16 tier, 128x64 tiles -> 1024 blocks) ----
    mg1(128, 64, l4h, LDH, tfe1, nullptr, 0, hah, 1024, 1024, 326, feb1, nullptr, 1, 0);
    mg1(128, 64, hah, 1024, tfe2, h_b, 1024, nullptr, 0, 1024, 1024, feb2, nullptr, 0, 0);
    k_maxpart<<<dim3(4, 32), 256, 0, stream>>>(h_b, gpart);
    k_gproj<<<8, 256, 0, stream>>>(gpart, mw1, mb1, gproj);

    // ---- head (bf16 tier; mw4 fuses log_softmax and writes d_out) ----
    mg1(128, 64, l4h, LDH, tmw1, nullptr, 0, bAh, 256, 256, 326, nullptr, gproj, 1, 0);
    mg1(128, 64, bAh, 256, tmw2, nullptr, 0, bBh, 256, 256, 256, mb2, nullptr, 1, 0);
    mg1(64, 64, bBh, 256, tmw3, nullptr, 0, bCh, 128, 128, 256, mb3, nullptr, 1, 0);
    mg1(64, 64, bCh, 128, tmw4, (float*)d_out, 50, nullptr, 0, 50, 128, mb4, nullptr, 0, 1);
}

// Round 15
// 670.071 us; speedup vs baseline: 1.1890x; 1.1310x over previous
//
#include <hip/hip_runtime.h>
#include <hip/hip_bf16.h>
#include <hip/amd_detail/amd_hip_vector_types.h>

#define NPTS 8192
#define PP 2048
#define KNN 30
#define KTOT 31
#define HEADS 3
#define LDH 352   // padded ld for link4 hi/lo (bf16): >= Kpad32(326), mult of 8
#define NSEG 10

typedef __attribute__((ext_vector_type(8))) short short8;
typedef __attribute__((ext_vector_type(4))) float floatx4;
typedef __attribute__((ext_vector_type(4))) unsigned int uint4_t;
typedef unsigned short ushort_t;
typedef unsigned int uint_t;

__device__ inline ushort_t f2bs(float v) {
    __hip_bfloat16 b = __float2bfloat16(v);
    return *reinterpret_cast<ushort_t*>(&b);
}
__device__ inline float bs2f(ushort_t u) {
    __hip_bfloat16 b = *reinterpret_cast<__hip_bfloat16*>(&u);
    return __bfloat162float(b);
}
__device__ inline void split2(float v, ushort_t& h, ushort_t& l) {
    h = f2bs(v);
    l = f2bs(v - bs2f(h));
}
// order-preserving fp32 <-> uint mapping for atomic max
__device__ inline uint_t fenc(float f) {
    uint_t b = __float_as_uint(f);
    return (b & 0x80000000u) ? ~b : (b | 0x80000000u);
}
__device__ inline float fdec(uint_t e) {
    return __uint_as_float((e & 0x80000000u) ? (e & 0x7FFFFFFFu) : ~e);
}

// ---------------- build x0 (hi/lo) into link4 cols 0..5 ----------------
__global__ void k_build_x0(const float* __restrict__ x, const float* __restrict__ pos,
                           ushort_t* __restrict__ lh, ushort_t* __restrict__ ll) {
    int i = blockIdx.x * blockDim.x + threadIdx.x;
    if (i >= NPTS * 6) return;
    int n = i / 6, c = i % 6;
    float v = (c < 3) ? x[n * 3 + c] : pos[n * 3 + (c - 3)];
    ushort_t h, l; split2(v, h, l);
    lh[(size_t)n * LDH + c] = h;
    ll[(size_t)n * LDH + c] = l;
}

// ---------------- fused weight transpose + split (10 MFMA weights, one launch) ----------
struct WArgs {
    const float* src[NSEG];
    ushort_t* dst[NSEG];
    int K[NSEG], N[NSEG], Kp[NSEG], t0[NSEG];
};
__global__ void k_wsplit_all(WArgs a) {
    int bt = blockIdx.x;
    int si = 0;
#pragma unroll
    for (int i = 1; i < NSEG; i++) if (bt >= a.t0[i]) si = i;
    int t = bt - a.t0[si];
    int K_ = a.K[si], N_ = a.N[si], Kp = a.Kp[si];
    const float* src = a.src[si];
    ushort_t* dh = a.dst[si];
    ushort_t* dl = dh + (size_t)Kp * N_;
    int tX = (N_ + 31) >> 5;
    int k0 = (t / tX) * 32, n0 = (t % tX) * 32;
    __shared__ float tt[32][33];
    int c = threadIdx.x & 31, r8 = threadIdx.x >> 5;
#pragma unroll
    for (int i = 0; i < 4; i++) {
        int r = r8 + i * 8;
        int k = k0 + r, n = n0 + c;
        tt[r][c] = (k < K_ && n < N_) ? src[(size_t)k * N_ + n] : 0.f;
    }
    __syncthreads();
#pragma unroll
    for (int i = 0; i < 4; i++) {
        int r = r8 + i * 8;
        int n = n0 + r, k = k0 + c;
        if (n < N_) {
            float v = tt[c][r];
            ushort_t h, l; split2(v, h, l);
            dh[(size_t)n * Kp + k] = h;
            dl[(size_t)n * Kp + k] = l;
        }
    }
}

// -------- pure-bf16 MFMA GEMM, software-pipelined; optional fused log_softmax
// or fused column-max reduction (gmax != null: no C write, atomicMax encoded fp32) --------
template<int MT, int NT>
__global__ __launch_bounds__(256)
void k_mgemm1(const ushort_t* __restrict__ A, int lda,
              const ushort_t* __restrict__ W, int ldw,
              float* __restrict__ Cf, int ldc,
              ushort_t* __restrict__ Ch, int ldh,
              int Ndim, int K,
              const float* __restrict__ bias1, const float* __restrict__ bias2,
              int relu, int lsm, uint_t* __restrict__ gmax) {
    constexpr int MTW = MT / 64;
    constexpr int NTT = NT / 16;
    __shared__ ushort_t As[2][MT * 40];
    __shared__ ushort_t Bs[2][NT * 40];
    __shared__ uint_t smax[NT];
    int tid = threadIdx.x;
    int w = tid >> 6, lane = tid & 63;
    int quad = lane >> 4, l16 = lane & 15;
    int m0 = blockIdx.x * MT, n0 = blockIdx.y * NT;
    uint4_t pa[MT / 64], pb[NT / 64];
    auto prefetch = [&](int k0) {
#pragma unroll
        for (int rep = 0; rep < MT / 64; rep++) {
            int idx = tid + rep * 256;
            int row = idx >> 2, q = idx & 3;
            pa[rep] = *(const uint4_t*)(A + (size_t)(m0 + row) * lda + k0 + q * 8);
        }
#pragma unroll
        for (int rep = 0; rep < NT / 64; rep++) {
            int idx = tid + rep * 256;
            int row = idx >> 2, q = idx & 3;
            uint4_t v = {0, 0, 0, 0};
            if (n0 + row < Ndim) v = *(const uint4_t*)(W + (size_t)(n0 + row) * ldw + k0 + q * 8);
            pb[rep] = v;
        }
    };
    auto stage = [&](int buf) {
#pragma unroll
        for (int rep = 0; rep < MT / 64; rep++) {
            int idx = tid + rep * 256;
            int row = idx >> 2, q = idx & 3;
            *(uint4_t*)&As[buf][row * 40 + q * 8] = pa[rep];
        }
#pragma unroll
        for (int rep = 0; rep < NT / 64; rep++) {
            int idx = tid + rep * 256;
            int row = idx >> 2, q = idx & 3;
            *(uint4_t*)&Bs[buf][row * 40 + q * 8] = pb[rep];
        }
    };
    if (gmax) {
        for (int idx = tid; idx < NT; idx += 256) smax[idx] = 0u;
    }
    floatx4 acc[MTW][NTT] = {};
    prefetch(0);
    stage(0);
    __syncthreads();
    int cur = 0;
    for (int k0 = 0; k0 < K; k0 += 32) {
        bool more = (k0 + 32 < K);
        if (more) prefetch(k0 + 32);
        short8 ah[MTW];
#pragma unroll
        for (int mt = 0; mt < MTW; mt++) {
            int r = w * (MT / 4) + mt * 16 + l16;
            ah[mt] = *(short8*)&As[cur][r * 40 + quad * 8];
        }
#pragma unroll
        for (int nt = 0; nt < NTT; nt++) {
            int r = nt * 16 + l16;
            short8 bh = *(short8*)&Bs[cur][r * 40 + quad * 8];
#pragma unroll
            for (int mt = 0; mt < MTW; mt++)
                acc[mt][nt] = __builtin_amdgcn_mfma_f32_16x16x32_bf16(ah[mt], bh, acc[mt][nt], 0, 0, 0);
        }
        if (more) stage(cur ^ 1);
        __syncthreads();
        cur ^= 1;
    }
    if (lsm) {
        // fused log_softmax over Ndim (<= NT) cols; whole row lives in this block
#pragma unroll
        for (int mt = 0; mt < MTW; mt++) {
#pragma unroll
            for (int r = 0; r < 4; r++) {
                float vv[NTT];
                float mrow = -3e38f;
#pragma unroll
                for (int nt = 0; nt < NTT; nt++) {
                    int n = n0 + nt * 16 + l16;
                    float val = (n < Ndim) ? acc[mt][nt][r] + bias1[n] : -3e38f;
                    vv[nt] = val;
                    mrow = fmaxf(mrow, val);
                }
#pragma unroll
                for (int off = 8; off >= 1; off >>= 1)
                    mrow = fmaxf(mrow, __shfl_xor(mrow, off, 64));
                float s = 0.f;
#pragma unroll
                for (int nt = 0; nt < NTT; nt++)
                    if (vv[nt] > -1e38f) s += expf(vv[nt] - mrow);
#pragma unroll
                for (int off = 8; off >= 1; off >>= 1)
                    s += __shfl_xor(s, off, 64);
                float lse = mrow + logf(s);
                int m = m0 + w * (MT / 4) + mt * 16 + quad * 4 + r;
#pragma unroll
                for (int nt = 0; nt < NTT; nt++) {
                    int n = n0 + nt * 16 + l16;
                    if (n < Ndim) Cf[(size_t)m * ldc + n] = vv[nt] - lse;
                }
            }
        }
        return;
    }
    if (gmax) {
        // fused column max: no C write; LDS atomicMax then one global atomicMax/col
#pragma unroll
        for (int mt = 0; mt < MTW; mt++) {
#pragma unroll
            for (int nt = 0; nt < NTT; nt++) {
#pragma unroll
                for (int r = 0; r < 4; r++) {
                    float v = acc[mt][nt][r] + bias1[nt * 16 + l16 + n0];
                    atomicMax(&smax[nt * 16 + l16], fenc(v));
                }
            }
        }
        __syncthreads();
        for (int idx = tid; idx < NT; idx += 256)
            atomicMax(&gmax[n0 + idx], smax[idx]);
        return;
    }
#pragma unroll
    for (int mt = 0; mt < MTW; mt++) {
#pragma unroll
        for (int nt = 0; nt < NTT; nt++) {
#pragma unroll
            for (int r = 0; r < 4; r++) {
                int m = m0 + w * (MT / 4) + mt * 16 + quad * 4 + r;
                int n = n0 + nt * 16 + l16;
                if (n < Ndim) {
                    float v = acc[mt][nt][r];
                    if (bias1) v += bias1[n];
                    if (bias2) v += bias2[n];
                    if (relu && v < 0.f) v = 0.f;
                    if (Cf) Cf[(size_t)m * ldc + n] = v;
                    if (Ch) Ch[(size_t)m * ldh + n] = f2bs(v);
                }
            }
        }
    }
}

// ---------------- split-bf16 (3-term) MFMA GEMM, single-buffered (small K only) -----
__global__ __launch_bounds__(256)
void k_mgemm3(const ushort_t* __restrict__ Ah, const ushort_t* __restrict__ Al, int lda,
              const ushort_t* __restrict__ Wh, const ushort_t* __restrict__ Wl, int ldw,
              float* __restrict__ Cf, int ldc,
              int Ndim, int K) {
    constexpr int NTT = 4;
    __shared__ ushort_t AsH[64 * 40], BsH[64 * 40], AsL[64 * 40], BsL[64 * 40];
    int tid = threadIdx.x;
    int w = tid >> 6, lane = tid & 63;
    int quad = lane >> 4, l16 = lane & 15;
    int m0 = blockIdx.y * 64, n0 = blockIdx.x * 64;
    floatx4 acc[NTT] = {};
    for (int k0 = 0; k0 < K; k0 += 32) {
        {
            int row = tid >> 2, q = tid & 3;
            size_t go = (size_t)(m0 + row) * lda + k0 + q * 8;
            *(uint4_t*)&AsH[row * 40 + q * 8] = *(const uint4_t*)(Ah + go);
            *(uint4_t*)&AsL[row * 40 + q * 8] = *(const uint4_t*)(Al + go);
            uint4_t vh = {0, 0, 0, 0}, vl = {0, 0, 0, 0};
            size_t gw = (size_t)(n0 + row) * ldw + k0 + q * 8;
            if (n0 + row < Ndim) { vh = *(const uint4_t*)(Wh + gw); vl = *(const uint4_t*)(Wl + gw); }
            *(uint4_t*)&BsH[row * 40 + q * 8] = vh;
            *(uint4_t*)&BsL[row * 40 + q * 8] = vl;
        }
        __syncthreads();
        short8 ah, al;
        {
            int r = w * 16 + l16;
            ah = *(short8*)&AsH[r * 40 + quad * 8];
            al = *(short8*)&AsL[r * 40 + quad * 8];
        }
#pragma unroll
        for (int nt = 0; nt < NTT; nt++) {
            int r = nt * 16 + l16;
            short8 bh = *(short8*)&BsH[r * 40 + quad * 8];
            short8 bl = *(short8*)&BsL[r * 40 + quad * 8];
            acc[nt] = __builtin_amdgcn_mfma_f32_16x16x32_bf16(ah, bh, acc[nt], 0, 0, 0);
            acc[nt] = __builtin_amdgcn_mfma_f32_16x16x32_bf16(ah, bl, acc[nt], 0, 0, 0);
            acc[nt] = __builtin_amdgcn_mfma_f32_16x16x32_bf16(al, bh, acc[nt], 0, 0, 0);
        }
        __syncthreads();
    }
#pragma unroll
    for (int nt = 0; nt < NTT; nt++) {
#pragma unroll
        for (int r = 0; r < 4; r++) {
            int m = m0 + w * 16 + quad * 4 + r;
            int n = n0 + nt * 16 + l16;
            if (n < Ndim) Cf[(size_t)m * ldc + n] = acc[nt][r];
        }
    }
}

// ---------------- exact-fp32 VALU GEMM for small N, K%64==0: LDS-tiled W ----------
template<int N_, int NPB>
__global__ __launch_bounds__(NPB * N_)
void k_vgemm(const float* __restrict__ A, int lda, int K_,
             const float* __restrict__ W, const float* __restrict__ bias,
             ushort_t* __restrict__ Ch, ushort_t* __restrict__ Cl, int ldh,
             float* __restrict__ Cf, int ldc, int relu) {
    constexpr int KT = 64;
    __shared__ float Ws[KT * N_];
    __shared__ float As[NPB * KT];
    int t = threadIdx.x;
    int n0 = blockIdx.x * NPB;
    int node = t / N_, j = t % N_;
    float acc = bias ? bias[j] : 0.f;
    for (int k0 = 0; k0 < K_; k0 += KT) {
        for (int idx = t; idx < KT * N_; idx += NPB * N_)
            Ws[idx] = W[(size_t)(k0 + idx / N_) * N_ + idx % N_];
        for (int idx = t; idx < NPB * KT; idx += NPB * N_)
            As[idx] = A[(size_t)(n0 + idx / KT) * lda + k0 + idx % KT];
        __syncthreads();
#pragma unroll
        for (int kk = 0; kk < KT; kk++)
            acc += As[node * KT + kk] * Ws[kk * N_ + j];
        __syncthreads();
    }
    if (relu && acc < 0.f) acc = 0.f;
    size_t m = n0 + node;
    if (Cf) Cf[m * ldc + j] = acc;
    if (Ch) {
        ushort_t h = f2bs(acc);
        Ch[m * ldh + j] = h;
        if (Cl) Cl[m * ldh + j] = f2bs(acc - bs2f(h));
    }
}

// ---------------- tw1: xh = [x|pos] @ w1, exact fp32 (K=6) ----------------
__global__ void k_tw1(const float* __restrict__ x, const float* __restrict__ pos,
                      const float* __restrict__ w1, float* __restrict__ xh) {
    int t = blockIdx.x * blockDim.x + threadIdx.x;
    if (t >= NPTS * 192) return;
    int n = t / 192, j = t % 192;
    float acc = 0.f;
#pragma unroll
    for (int c = 0; c < 3; c++) {
        acc += x[n * 3 + c] * w1[c * 192 + j];
        acc += pos[n * 3 + c] * w1[(3 + c) * 192 + j];
    }
    xh[(size_t)n * 192 + j] = acc;
}

// ---------------- split-bf16 MFMA pairwise distances -> packed sort keys -----------
// sq computed in-kernel from staged tiles (threads 0..191), strict k-ascending order
// (bitwise-identical to the old standalone sqnorm kernel).
__global__ __launch_bounds__(256)
void k_mdist(const ushort_t* __restrict__ Lh, const ushort_t* __restrict__ Ll,
             int co, int C, uint_t* __restrict__ keys) {
    __shared__ ushort_t AsH[128 * 40], AsL[128 * 40], BsH[64 * 40], BsL[64 * 40];
    __shared__ float sqa[128], sqb[64];
    int tid = threadIdx.x;
    int w = tid >> 6, lane = tid & 63;
    int quad = lane >> 4, l16 = lane & 15;
    int b = blockIdx.z, cb = b * PP;
    int i0 = blockIdx.y * 128, j0 = blockIdx.x * 64;
    floatx4 acc[2][4] = {};
    float sacc = 0.f;
    for (int k0 = 0; k0 < C; k0 += 32) {
#pragma unroll
        for (int rep = 0; rep < 8; rep++) {
            int d = tid + rep * 256;
            int row = d >> 4, c2 = d & 15;
            size_t gi = ((size_t)(cb + i0 + row) * LDH + co + k0 + c2 * 2) >> 1;
            *(uint_t*)&AsH[row * 40 + c2 * 2] = ((const uint_t*)Lh)[gi];
            *(uint_t*)&AsL[row * 40 + c2 * 2] = ((const uint_t*)Ll)[gi];
        }
#pragma unroll
        for (int rep = 0; rep < 4; rep++) {
            int d = tid + rep * 256;
            int row = d >> 4, c2 = d & 15;
            size_t gi = ((size_t)(cb + j0 + row) * LDH + co + k0 + c2 * 2) >> 1;
            *(uint_t*)&BsH[row * 40 + c2 * 2] = ((const uint_t*)Lh)[gi];
            *(uint_t*)&BsL[row * 40 + c2 * 2] = ((const uint_t*)Ll)[gi];
        }
        __syncthreads();
        // per-row squared-norm accumulation from staged tiles (pad cols are zeros)
        if (tid < 128) {
#pragma unroll
            for (int kk = 0; kk < 16; kk++) {
                uint_t ph = *(uint_t*)&AsH[tid * 40 + kk * 2];
                uint_t pl = *(uint_t*)&AsL[tid * 40 + kk * 2];
                float v0 = bs2f((ushort_t)(ph & 0xFFFFu)) + bs2f((ushort_t)(pl & 0xFFFFu));
                sacc += v0 * v0;
                float v1 = bs2f((ushort_t)(ph >> 16)) + bs2f((ushort_t)(pl >> 16));
                sacc += v1 * v1;
            }
        } else if (tid < 192) {
            int row = tid - 128;
#pragma unroll
            for (int kk = 0; kk < 16; kk++) {
                uint_t ph = *(uint_t*)&BsH[row * 40 + kk * 2];
                uint_t pl = *(uint_t*)&BsL[row * 40 + kk * 2];
                float v0 = bs2f((ushort_t)(ph & 0xFFFFu)) + bs2f((ushort_t)(pl & 0xFFFFu));
                sacc += v0 * v0;
                float v1 = bs2f((ushort_t)(ph >> 16)) + bs2f((ushort_t)(pl >> 16));
                sacc += v1 * v1;
            }
        }
        short8 ah[2], al[2];
#pragma unroll
        for (int mt = 0; mt < 2; mt++) {
            int r = w * 32 + mt * 16 + l16;
            ah[mt] = *(short8*)&AsH[r * 40 + quad * 8];
            al[mt] = *(short8*)&AsL[r * 40 + quad * 8];
        }
#pragma unroll
        for (int nt = 0; nt < 4; nt++) {
            int r = nt * 16 + l16;
            short8 bh = *(short8*)&BsH[r * 40 + quad * 8];
            short8 bl = *(short8*)&BsL[r * 40 + quad * 8];
#pragma unroll
            for (int mt = 0; mt < 2; mt++) {
                acc[mt][nt] = __builtin_amdgcn_mfma_f32_16x16x32_bf16(ah[mt], bh, acc[mt][nt], 0, 0, 0);
                acc[mt][nt] = __builtin_amdgcn_mfma_f32_16x16x32_bf16(ah[mt], bl, acc[mt][nt], 0, 0, 0);
                acc[mt][nt] = __builtin_amdgcn_mfma_f32_16x16x32_bf16(al[mt], bh, acc[mt][nt], 0, 0, 0);
            }
        }
        __syncthreads();
    }
    if (tid < 128) sqa[tid] = sacc;
    else if (tid < 192) sqb[tid - 128] = sacc;
    __syncthreads();
#pragma unroll
    for (int mt = 0; mt < 2; mt++) {
#pragma unroll
        for (int nt = 0; nt < 4; nt++) {
#pragma unroll
            for (int r = 0; r < 4; r++) {
                int li = w * 32 + mt * 16 + quad * 4 + r;
                int lj = nt * 16 + l16;
                int il = i0 + li, jl = j0 + lj;
                float dd = sqa[li] + sqb[lj] - 2.f * acc[mt][nt][r];
                dd = (il == jl) ? 3e9f : fmaxf(dd, 0.f);
                keys[(size_t)(cb + il) * PP + jl] =
                    (__float_as_uint(dd) & 0xFFFFF800u) | (uint_t)jl;
            }
        }
    }
}

// ---------------- top-30 smallest per row via packed u32 keys ----------------
__global__ __launch_bounds__(256)
void k_topk(const uint_t* __restrict__ keys, int* __restrict__ nbr) {
    int r = blockIdx.x * 4 + (threadIdx.x >> 6);
    int lane = threadIdx.x & 63;
    int base = (r / PP) * PP;
    const uint_t* row = keys + (size_t)r * PP;
    uint_t v[32];
#pragma unroll
    for (int j = 0; j < 8; j++)
        *(uint4_t*)&v[j * 4] = *(const uint4_t*)(row + lane * 4 + j * 256);
    uint_t g[8];
#pragma unroll
    for (int j = 0; j < 8; j++)
        g[j] = min(min(v[j * 4], v[j * 4 + 1]), min(v[j * 4 + 2], v[j * 4 + 3]));
    uint_t lv = g[0];
#pragma unroll
    for (int j = 1; j < 8; j++) lv = min(lv, g[j]);
    for (int sel = 0; sel < KNN; sel++) {
        uint_t bk = lv;
#pragma unroll
        for (int off = 32; off > 0; off >>= 1)
            bk = min(bk, (uint_t)__shfl_xor((int)bk, off, 64));
        uint_t bks = __builtin_amdgcn_readfirstlane(bk);
        if (lane == 0) nbr[r * KTOT + sel] = base + (int)(bks & 0x7FFu);
        int grp = (int)((bks & 0x7FFu) >> 8);
#pragma unroll
        for (int jj = 0; jj < 8; jj++)
            if (grp == jj) {
#pragma unroll
                for (int t = 0; t < 4; t++)
                    v[jj * 4 + t] = (v[jj * 4 + t] == bks) ? 0xFFFFFFFFu : v[jj * 4 + t];
                g[jj] = min(min(v[jj * 4], v[jj * 4 + 1]), min(v[jj * 4 + 2], v[jj * 4 + 3]));
            }
        lv = g[0];
#pragma unroll
        for (int j = 1; j < 8; j++) lv = min(lv, g[j]);
    }
    if (lane == 0) nbr[r * KTOT + KNN] = r;
}

// ---------------- GAT source/target scores ----------------
__global__ void k_scores(const float* __restrict__ xh, int F,
                         const float* __restrict__ a_src,
                         const float* __restrict__ a_dst,
                         float* __restrict__ s, float* __restrict__ t) {
    int g = blockIdx.x * blockDim.x + threadIdx.x;
    if (g >= NPTS * HEADS) return;
    int n = g / HEADS, h = g % HEADS;
    const float* xr = xh + (size_t)n * (HEADS * F) + h * F;
    float ss = 0.f, tt = 0.f;
    for (int f = 0; f < F; f++) {
        float v = xr[f];
        ss += v * a_src[h * F + f];
        tt += v * a_dst[h * F + f];
    }
    s[g] = ss;
    t[g] = tt;
}

// ---------------- GAT edge-softmax + aggregate (fp32 out or bf16-hi out) ----------------
// XCD-aware block swizzle: cloud = bid & 3 keeps each cloud's xh slab in 2 XCD L2s.
__global__ void k_gat(const float* __restrict__ xh, int F,
                      const float* __restrict__ s, const float* __restrict__ t,
                      const int* __restrict__ nbr,
                      const float* __restrict__ bias,
                      float* __restrict__ outf, ushort_t* __restrict__ oh) {
    int HF = HEADS * F;
    __shared__ int srcs[KTOT];
    __shared__ float alpha[KTOT * HEADS];
    int i = (blockIdx.x & 3) * PP + (blockIdx.x >> 2);
    int tid = threadIdx.x;
    if (tid < KTOT) srcs[tid] = nbr[i * KTOT + tid];
    __syncthreads();
    if (tid < KTOT * HEADS) {
        int k = tid / HEADS, h = tid % HEADS;
        float e = s[srcs[k] * HEADS + h] + t[i * HEADS + h];
        if (e < 0.f) e *= 0.2f;
        alpha[tid] = e;
    }
    __syncthreads();
    if (tid < HEADS) {
        int h = tid;
        float m = -3e38f;
        for (int k = 0; k < KTOT; k++) m = fmaxf(m, alpha[k * HEADS + h]);
        float sum = 0.f;
        for (int k = 0; k < KTOT; k++) {
            float ex = expf(alpha[k * HEADS + h] - m);
            alpha[k * HEADS + h] = ex;
            sum += ex;
        }
        float inv = 1.f / sum;
        for (int k = 0; k < KTOT; k++) alpha[k * HEADS + h] *= inv;
    }
    __syncthreads();
    int h = tid / F;
    float acc = 0.f;
    for (int k = 0; k < KTOT; k++)
        acc += alpha[k * HEADS + h] * xh[(size_t)srcs[k] * HF + tid];
    float v = acc + bias[tid];
    if (oh) oh[(size_t)i * HF + tid] = f2bs(v);
    else outf[(size_t)i * HF + tid] = v;
}

// ---------------- gproj: decode fused column max + split-K matmul ----------------
__global__ void k_gproj(const uint_t* __restrict__ genc,
                        const float* __restrict__ mw1,
                        const float* __restrict__ mb1,
                        float* __restrict__ gproj) {
    __shared__ float gs[128];
    int kb = blockIdx.x;           // 8 blocks x 128 k
    int t = threadIdx.x;           // 256
    if (t < 128) gs[t] = fdec(genc[kb * 128 + t]);
    __syncthreads();
    float acc = (kb == 0) ? mb1[t] : 0.f;
    for (int k = 0; k < 128; k++)
        acc += gs[k] * mw1[(size_t)(326 + kb * 128 + k) * 256 + t];
    atomicAdd(&gproj[t], acc);
}

// ---------------- host side ----------------
struct WT { ushort_t *h, *l; int kp; };

extern "C" void kernel_launch(void* const* d_in, const int* in_sizes, int n_in,
                              void* d_out, int out_size, void* d_ws, size_t ws_size,
                              hipStream_t stream) {
    (void)in_sizes; (void)n_in; (void)out_size; (void)ws_size;
    const float* x    = (const float*)d_in[0];
    const float* pos  = (const float*)d_in[1];
    const float* w1   = (const float*)d_in[3];
    const float* as1  = (const float*)d_in[4];
    const float* ad1  = (const float*)d_in[5];
    const float* b1   = (const float*)d_in[6];
    const float* ml1w = (const float*)d_in[7];
    const float* ml1b = (const float*)d_in[8];
    const float* w2   = (const float*)d_in[9];
    const float* as2  = (const float*)d_in[10];
    const float* ad2  = (const float*)d_in[11];
    const float* b2   = (const float*)d_in[12];
    const float* ml2w = (const float*)d_in[13];
    const float* ml2b = (const float*)d_in[14];
    const float* w3   = (const float*)d_in[15];
    const float* as3  = (const float*)d_in[16];
    const float* ad3  = (const float*)d_in[17];
    const float* b3   = (const float*)d_in[18];
    const float* ml3w = (const float*)d_in[19];
    const float* ml3b = (const float*)d_in[20];
    const float* w4   = (const float*)d_in[21];
    const float* as4  = (const float*)d_in[22];
    const float* ad4  = (const float*)d_in[23];
    const float* b4   = (const float*)d_in[24];
    const float* ml4w = (const float*)d_in[25];
    const float* ml4b = (const float*)d_in[26];
    const float* few1 = (const float*)d_in[27];
    const float* feb1 = (const float*)d_in[28];
    const float* few2 = (const float*)d_in[29];
    const float* feb2 = (const float*)d_in[30];
    const float* mw1  = (const float*)d_in[31];
    const float* mb1  = (const float*)d_in[32];
    const float* mw2  = (const float*)d_in[33];
    const float* mb2  = (const float*)d_in[34];
    const float* mw3  = (const float*)d_in[35];
    const float* mb3  = (const float*)d_in[36];
    const float* mw4  = (const float*)d_in[37];
    const float* mb4  = (const float*)d_in[38];

    float* Wb = (float*)d_ws;
    size_t off = 0;
    auto alloc = [&](size_t n) { float* p = Wb + off; off += (n + 63) & ~(size_t)63; return p; };

    float*    dist = alloc((size_t)NPTS * PP);                  // 67 MB aliased region
    ushort_t* l4h  = (ushort_t*)alloc((size_t)NPTS * LDH / 2);
    ushort_t* l4l  = (ushort_t*)alloc((size_t)NPTS * LDH / 2);
    float*    gof  = alloc((size_t)NPTS * 384);                 // gat fp32 out (12.6MB)
    ushort_t* goh  = (ushort_t*)alloc((size_t)NPTS * 384 / 2);  // stage-4 gat bf16 out
    float* sbuf  = alloc((size_t)NPTS * HEADS);
    float* tbuf  = alloc((size_t)NPTS * HEADS);
    uint_t* genc = (uint_t*)alloc(1024);                        // encoded col maxima
    float* gproj = alloc(256);
    int*   nbr   = (int*)alloc((size_t)NPTS * KTOT);
    ushort_t* wtpool = (ushort_t*)alloc(1831168 + 128);

    // aliases inside dist region (disjoint lifetimes)
    char* d0 = (char*)dist;
    uint_t*   dkey = (uint_t*)dist;                             // packed knn keys
    float*    xh   = dist;                                      // stages 1-4 (<=12.6MB)
    ushort_t* hah  = (ushort_t*)d0;                             // fe1 out hi (16.8MB)
    ushort_t* bBh  = (ushort_t*)(d0 + (size_t)NPTS * 1024 * 2); // mw2 out hi
    ushort_t* bAh = (ushort_t*)gof;                             // mw1 out hi (gof dead after ml4)
    ushort_t* bCh = (ushort_t*)gof;                             // mw3 out hi (bAh dead)

    // ---- zero link4 planes + accumulators ----
    hipMemsetAsync(l4h, 0, (size_t)NPTS * LDH * 4, stream);
    hipMemsetAsync(gproj, 0, 256 * 4, stream);
    hipMemsetAsync(genc, 0, 1024 * 4, stream);

    // ---- fused weight transpose+split (MFMA weights only) ----
    WArgs wa;
    WT wt[NSEG];
    {
        const float* srcs[NSEG] = {w2, w3, w4, ml4w, few1, few2, mw1, mw2, mw3, mw4};
        int Ks[NSEG] = {70, 134, 198, 384, 326, 1024, 326, 256, 256, 128};
        int Ns[NSEG] = {192, 192, 384, 128, 1024, 1024, 256, 256, 128, 50};
        size_t wo = 0; int tiles = 0;
        for (int i = 0; i < NSEG; i++) {
            int kp = (Ks[i] + 31) & ~31;
            wa.src[i] = srcs[i];
            wa.dst[i] = wtpool + wo;
            wa.K[i] = Ks[i]; wa.N[i] = Ns[i]; wa.Kp[i] = kp;
            wa.t0[i] = tiles;
            wt[i] = { wtpool + wo, wtpool + wo + (size_t)kp * Ns[i], kp };
            wo += (size_t)2 * kp * Ns[i];
            tiles += (kp / 32) * ((Ns[i] + 31) / 32);
        }
        k_wsplit_all<<<tiles, 256, 0, stream>>>(wa);
    }
    WT tw2 = wt[0], tw3 = wt[1], tw4 = wt[2], tml4 = wt[3], tfe1 = wt[4], tfe2 = wt[5],
       tmw1 = wt[6], tmw2 = wt[7], tmw3 = wt[8], tmw4 = wt[9];

    auto mg3 = [&](const ushort_t* Ah, const ushort_t* Al, int lda, WT t,
                   float* Cf, int ldc, int Nd, int K) {
        dim3 g((Nd + 63) / 64, NPTS / 64);
        k_mgemm3<<<g, 256, 0, stream>>>(Ah, Al, lda, t.h, t.l, t.kp, Cf, ldc, Nd, K);
    };
    auto mg1 = [&](int MT, int NT, const ushort_t* Ah, int lda, WT t,
                   float* Cf, int ldc, ushort_t* Ch, int ldhh,
                   int Nd, int K, const float* bb1, const float* bb2,
                   int relu, int lsm, uint_t* gmax) {
        dim3 g(NPTS / MT, (Nd + NT - 1) / NT);
        if (MT == 128 && NT == 64)
            k_mgemm1<128, 64><<<g, 256, 0, stream>>>(Ah, lda, t.h, t.kp, Cf, ldc, Ch, ldhh, Nd, K, bb1, bb2, relu, lsm, gmax);
        else
            k_mgemm1<64, 64><<<g, 256, 0, stream>>>(Ah, lda, t.h, t.kp, Cf, ldc, Ch, ldhh, Nd, K, bb1, bb2, relu, lsm, gmax);
    };

    dim3 dgrid(PP / 64, PP / 128, 4);
    k_build_x0<<<(NPTS * 6 + 255) / 256, 256, 0, stream>>>(x, pos, l4h, l4l);

    // ---- stage 1: knn on x0 (C=6), GAT1 (exact fp32 path -> x1) ----
    k_mdist<<<dgrid, 256, 0, stream>>>(l4h, l4l, 0, 6, dkey);
    k_topk<<<NPTS / 4, 256, 0, stream>>>(dkey, nbr);
    k_tw1<<<(NPTS * 192 + 255) / 256, 256, 0, stream>>>(x, pos, w1, xh);
    k_scores<<<(NPTS * HEADS + 255) / 256, 256, 0, stream>>>(xh, 64, as1, ad1, sbuf, tbuf);
    k_gat<<<NPTS, 192, 0, stream>>>(xh, 64, sbuf, tbuf, nbr, b1, gof, nullptr);
    k_vgemm<64, 4><<<NPTS / 4, 256, 0, stream>>>(gof, 192, 192, ml1w, ml1b,
        l4h + 6, l4l + 6, LDH, nullptr, 0, 0);

    // ---- stage 2: knn on x1 (C=64), GAT2 (fp32 path -> x2) ----
    k_mdist<<<dgrid, 256, 0, stream>>>(l4h, l4l, 6, 64, dkey);
    k_topk<<<NPTS / 4, 256, 0, stream>>>(dkey, nbr);
    mg3(l4h, l4l, LDH, tw2, xh, 192, 192, 70);
    k_scores<<<(NPTS * HEADS + 255) / 256, 256, 0, stream>>>(xh, 64, as2, ad2, sbuf, tbuf);
    k_gat<<<NPTS, 192, 0, stream>>>(xh, 64, sbuf, tbuf, nbr, b2, gof, nullptr);
    k_vgemm<64, 4><<<NPTS / 4, 256, 0, stream>>>(gof, 192, 192, ml2w, ml2b,
        l4h + 70, l4l + 70, LDH, nullptr, 0, 0);

    // ---- stage 3: knn on x2 (C=64), GAT3 (bf16 tier -> x3) ----
    k_mdist<<<dgrid, 256, 0, stream>>>(l4h, l4l, 70, 64, dkey);
    k_topk<<<NPTS / 4, 256, 0, stream>>>(dkey, nbr);
    mg1(64, 64, l4h, LDH, tw3, xh, 192, nullptr, 0, 192, 134, nullptr, nullptr, 0, 0, nullptr);
    k_scores<<<(NPTS * HEADS + 255) / 256, 256, 0, stream>>>(xh, 64, as3, ad3, sbuf, tbuf);
    k_gat<<<NPTS, 192, 0, stream>>>(xh, 64, sbuf, tbuf, nbr, b3, gof, nullptr);
    k_vgemm<64, 4><<<NPTS / 4, 256, 0, stream>>>(gof, 192, 192, ml3w, ml3b,
        l4h + 134, nullptr, LDH, nullptr, 0, 0);

    // ---- stage 4: GAT4 reuses stage-3 nbr (bf16 tier -> x4, MFMA ml4) ----
    mg1(64, 64, l4h, LDH, tw4, xh, 384, nullptr, 0, 384, 198, nullptr, nullptr, 0, 0, nullptr);
    k_scores<<<(NPTS * HEADS + 255) / 256, 256, 0, stream>>>(xh, 128, as4, ad4, sbuf, tbuf);
    k_gat<<<NPTS, 384, 0, stream>>>(xh, 128, sbuf, tbuf, nbr, b4, nullptr, goh);
    mg1(64, 64, goh, 384, tml4, nullptr, 0, l4h + 198, LDH, 128, 384, ml4b, nullptr, 0, 0, nullptr);

    // ---- fe_mlp: fe1 -> bf16 acts; fe2 -> fused global column max (no C write) ----
    mg1(128, 64, l4h, LDH, tfe1, nullptr, 0, hah, 1024, 1024, 326, feb1, nullptr, 1, 0, nullptr);
    mg1(128, 64, hah, 1024, tfe2, nullptr, 0, nullptr, 0, 1024, 1024, feb2, nullptr, 0, 0, genc);
    k_gproj<<<8, 256, 0, stream>>>(genc, mw1, mb1, gproj);

    // ---- head (bf16 tier; mw4 fuses log_softmax and writes d_out) ----
    mg1(128, 64, l4h, LDH, tmw1, nullptr, 0, bAh, 256, 256, 326, nullptr, gproj, 1, 0, nullptr);
    mg1(128, 64, bAh, 256, tmw2, nullptr, 0, bBh, 256, 256, 256, mb2, nullptr, 1, 0, nullptr);
    mg1(64, 64, bBh, 256, tmw3, nullptr, 0, bCh, 128, 128, 256, mb3, nullptr, 1, 0, nullptr);
    mg1(64, 64, bCh, 128, tmw4, (float*)d_out, 50, nullptr, 0, 50, 128, mb4, nullptr, 0, 1, nullptr);
}

// Round 17
// 617.021 us; speedup vs baseline: 1.2912x; 1.0860x over previous
//
#include <hip/hip_runtime.h>
#include <hip/hip_bf16.h>
#include <hip/amd_detail/amd_hip_vector_types.h>

#define NPTS 8192
#define PP 2048
#define KNN 30
#define KTOT 31
#define HEADS 3
#define LDH 352   // padded ld for link4 hi/lo (bf16): >= Kpad32(326), mult of 8
#define NSEG 10

typedef __attribute__((ext_vector_type(8))) short short8;
typedef __attribute__((ext_vector_type(4))) float floatx4;
typedef __attribute__((ext_vector_type(4))) unsigned int uint4_t;
typedef unsigned short ushort_t;
typedef unsigned int uint_t;

__device__ inline ushort_t f2bs(float v) {
    __hip_bfloat16 b = __float2bfloat16(v);
    return *reinterpret_cast<ushort_t*>(&b);
}
__device__ inline float bs2f(ushort_t u) {
    __hip_bfloat16 b = *reinterpret_cast<__hip_bfloat16*>(&u);
    return __bfloat162float(b);
}
__device__ inline void split2(float v, ushort_t& h, ushort_t& l) {
    h = f2bs(v);
    l = f2bs(v - bs2f(h));
}
// order-preserving fp32 <-> uint mapping for atomic max
__device__ inline uint_t fenc(float f) {
    uint_t b = __float_as_uint(f);
    return (b & 0x80000000u) ? ~b : (b | 0x80000000u);
}
__device__ inline float fdec(uint_t e) {
    return __uint_as_float((e & 0x80000000u) ? (e & 0x7FFFFFFFu) : ~e);
}

// ---------------- build x0 (hi/lo) into link4 cols 0..5 ----------------
__global__ void k_build_x0(const float* __restrict__ x, const float* __restrict__ pos,
                           ushort_t* __restrict__ lh, ushort_t* __restrict__ ll) {
    int i = blockIdx.x * blockDim.x + threadIdx.x;
    if (i >= NPTS * 6) return;
    int n = i / 6, c = i % 6;
    float v = (c < 3) ? x[n * 3 + c] : pos[n * 3 + (c - 3)];
    ushort_t h, l; split2(v, h, l);
    lh[(size_t)n * LDH + c] = h;
    ll[(size_t)n * LDH + c] = l;
}

// ---------------- tw1: xh = [x|pos] @ w1, exact fp32 (K=6) ----------------
// NOTE: xh aliases the dist/key region -> must run AFTER k_topk consumed the keys.
__global__ void k_tw1(const float* __restrict__ x, const float* __restrict__ pos,
                      const float* __restrict__ w1, float* __restrict__ xh) {
    int t = blockIdx.x * blockDim.x + threadIdx.x;
    if (t >= NPTS * 192) return;
    int n = t / 192, j = t % 192;
    float acc = 0.f;
#pragma unroll
    for (int c = 0; c < 3; c++) {
        acc += x[n * 3 + c] * w1[c * 192 + j];
        acc += pos[n * 3 + c] * w1[(3 + c) * 192 + j];
    }
    xh[(size_t)n * 192 + j] = acc;
}

// ---------------- fused weight transpose + split (10 MFMA weights, one launch) ----------
struct WArgs {
    const float* src[NSEG];
    ushort_t* dst[NSEG];
    int K[NSEG], N[NSEG], Kp[NSEG], t0[NSEG];
};
__global__ void k_wsplit_all(WArgs a) {
    int bt = blockIdx.x;
    int si = 0;
#pragma unroll
    for (int i = 1; i < NSEG; i++) if (bt >= a.t0[i]) si = i;
    int t = bt - a.t0[si];
    int K_ = a.K[si], N_ = a.N[si], Kp = a.Kp[si];
    const float* src = a.src[si];
    ushort_t* dh = a.dst[si];
    ushort_t* dl = dh + (size_t)Kp * N_;
    int tX = (N_ + 31) >> 5;
    int k0 = (t / tX) * 32, n0 = (t % tX) * 32;
    __shared__ float tt[32][33];
    int c = threadIdx.x & 31, r8 = threadIdx.x >> 5;
#pragma unroll
    for (int i = 0; i < 4; i++) {
        int r = r8 + i * 8;
        int k = k0 + r, n = n0 + c;
        tt[r][c] = (k < K_ && n < N_) ? src[(size_t)k * N_ + n] : 0.f;
    }
    __syncthreads();
#pragma unroll
    for (int i = 0; i < 4; i++) {
        int r = r8 + i * 8;
        int n = n0 + r, k = k0 + c;
        if (n < N_) {
            float v = tt[c][r];
            ushort_t h, l; split2(v, h, l);
            dh[(size_t)n * Kp + k] = h;
            dl[(size_t)n * Kp + k] = l;
        }
    }
}

// -------- pure-bf16 MFMA GEMM, software-pipelined; fusable epilogues:
//   lsm: log_softmax over Ndim cols;  gmax: column-max (no C write);
//   asrc/adst: GAT scores s,t (full-head per block if !satomic, else atomicAdd) --------
template<int MT, int NT>
__global__ __launch_bounds__(256)
void k_mgemm1(const ushort_t* __restrict__ A, int lda,
              const ushort_t* __restrict__ W, int ldw,
              float* __restrict__ Cf, int ldc,
              ushort_t* __restrict__ Ch, int ldh,
              int Ndim, int K,
              const float* __restrict__ bias1, const float* __restrict__ bias2,
              int relu, int lsm, uint_t* __restrict__ gmax,
              const float* __restrict__ asrc, const float* __restrict__ adst,
              float* __restrict__ sb, float* __restrict__ tb, int Fsc, int satomic) {
    constexpr int MTW = MT / 64;
    constexpr int NTT = NT / 16;
    __shared__ ushort_t As[2][MT * 40];
    __shared__ ushort_t Bs[2][NT * 40];
    __shared__ uint_t smax[NT];
    int tid = threadIdx.x;
    int w = tid >> 6, lane = tid & 63;
    int quad = lane >> 4, l16 = lane & 15;
    int m0 = blockIdx.x * MT, n0 = blockIdx.y * NT;
    uint4_t pa[MT / 64], pb[NT / 64];
    auto prefetch = [&](int k0) {
#pragma unroll
        for (int rep = 0; rep < MT / 64; rep++) {
            int idx = tid + rep * 256;
            int row = idx >> 2, q = idx & 3;
            pa[rep] = *(const uint4_t*)(A + (size_t)(m0 + row) * lda + k0 + q * 8);
        }
#pragma unroll
        for (int rep = 0; rep < NT / 64; rep++) {
            int idx = tid + rep * 256;
            int row = idx >> 2, q = idx & 3;
            uint4_t v = {0, 0, 0, 0};
            if (n0 + row < Ndim) v = *(const uint4_t*)(W + (size_t)(n0 + row) * ldw + k0 + q * 8);
            pb[rep] = v;
        }
    };
    auto stage = [&](int buf) {
#pragma unroll
        for (int rep = 0; rep < MT / 64; rep++) {
            int idx = tid + rep * 256;
            int row = idx >> 2, q = idx & 3;
            *(uint4_t*)&As[buf][row * 40 + q * 8] = pa[rep];
        }
#pragma unroll
        for (int rep = 0; rep < NT / 64; rep++) {
            int idx = tid + rep * 256;
            int row = idx >> 2, q = idx & 3;
            *(uint4_t*)&Bs[buf][row * 40 + q * 8] = pb[rep];
        }
    };
    if (gmax) {
        for (int idx = tid; idx < NT; idx += 256) smax[idx] = 0u;
    }
    floatx4 acc[MTW][NTT] = {};
    prefetch(0);
    stage(0);
    __syncthreads();
    int cur = 0;
    for (int k0 = 0; k0 < K; k0 += 32) {
        bool more = (k0 + 32 < K);
        if (more) prefetch(k0 + 32);
        short8 ah[MTW];
#pragma unroll
        for (int mt = 0; mt < MTW; mt++) {
            int r = w * (MT / 4) + mt * 16 + l16;
            ah[mt] = *(short8*)&As[cur][r * 40 + quad * 8];
        }
#pragma unroll
        for (int nt = 0; nt < NTT; nt++) {
            int r = nt * 16 + l16;
            short8 bh = *(short8*)&Bs[cur][r * 40 + quad * 8];
#pragma unroll
            for (int mt = 0; mt < MTW; mt++)
                acc[mt][nt] = __builtin_amdgcn_mfma_f32_16x16x32_bf16(ah[mt], bh, acc[mt][nt], 0, 0, 0);
        }
        if (more) stage(cur ^ 1);
        __syncthreads();
        cur ^= 1;
    }
    if (lsm) {
#pragma unroll
        for (int mt = 0; mt < MTW; mt++) {
#pragma unroll
            for (int r = 0; r < 4; r++) {
                float vv[NTT];
                float mrow = -3e38f;
#pragma unroll
                for (int nt = 0; nt < NTT; nt++) {
                    int n = n0 + nt * 16 + l16;
                    float val = (n < Ndim) ? acc[mt][nt][r] + bias1[n] : -3e38f;
                    vv[nt] = val;
                    mrow = fmaxf(mrow, val);
                }
#pragma unroll
                for (int off = 8; off >= 1; off >>= 1)
                    mrow = fmaxf(mrow, __shfl_xor(mrow, off, 64));
                float s = 0.f;
#pragma unroll
                for (int nt = 0; nt < NTT; nt++)
                    if (vv[nt] > -1e38f) s += expf(vv[nt] - mrow);
#pragma unroll
                for (int off = 8; off >= 1; off >>= 1)
                    s += __shfl_xor(s, off, 64);
                float lse = mrow + logf(s);
                int m = m0 + w * (MT / 4) + mt * 16 + quad * 4 + r;
#pragma unroll
                for (int nt = 0; nt < NTT; nt++) {
                    int n = n0 + nt * 16 + l16;
                    if (n < Ndim) Cf[(size_t)m * ldc + n] = vv[nt] - lse;
                }
            }
        }
        return;
    }
    if (gmax) {
#pragma unroll
        for (int mt = 0; mt < MTW; mt++) {
#pragma unroll
            for (int nt = 0; nt < NTT; nt++) {
#pragma unroll
                for (int r = 0; r < 4; r++) {
                    float v = acc[mt][nt][r] + bias1[nt * 16 + l16 + n0];
                    atomicMax(&smax[nt * 16 + l16], fenc(v));
                }
            }
        }
        __syncthreads();
        for (int idx = tid; idx < NT; idx += 256)
            atomicMax(&gmax[n0 + idx], smax[idx]);
        return;
    }
    if (asrc) {
        // fused GAT scores: this block's cols [n0,n0+NT) lie within head h = n0/Fsc
        int h = n0 / Fsc;
#pragma unroll
        for (int mt = 0; mt < MTW; mt++) {
#pragma unroll
            for (int r = 0; r < 4; r++) {
                float sp = 0.f, tp = 0.f;
#pragma unroll
                for (int nt = 0; nt < NTT; nt++) {
                    float v = acc[mt][nt][r];
                    sp += v * asrc[n0 + nt * 16 + l16];
                    tp += v * adst[n0 + nt * 16 + l16];
                }
#pragma unroll
                for (int off = 8; off >= 1; off >>= 1) {
                    sp += __shfl_xor(sp, off, 64);
                    tp += __shfl_xor(tp, off, 64);
                }
                if (l16 == 0) {
                    int m = m0 + w * (MT / 4) + mt * 16 + quad * 4 + r;
                    if (satomic) {
                        atomicAdd(&sb[m * HEADS + h], sp);
                        atomicAdd(&tb[m * HEADS + h], tp);
                    } else {
                        sb[m * HEADS + h] = sp;
                        tb[m * HEADS + h] = tp;
                    }
                }
            }
        }
    }
#pragma unroll
    for (int mt = 0; mt < MTW; mt++) {
#pragma unroll
        for (int nt = 0; nt < NTT; nt++) {
#pragma unroll
            for (int r = 0; r < 4; r++) {
                int m = m0 + w * (MT / 4) + mt * 16 + quad * 4 + r;
                int n = n0 + nt * 16 + l16;
                if (n < Ndim) {
                    float v = acc[mt][nt][r];
                    if (bias1) v += bias1[n];
                    if (bias2) v += bias2[n];
                    if (relu && v < 0.f) v = 0.f;
                    if (Cf) Cf[(size_t)m * ldc + n] = v;
                    if (Ch) Ch[(size_t)m * ldh + n] = f2bs(v);
                }
            }
        }
    }
}

// ---------------- split-bf16 (3-term) MFMA GEMM + optional fused GAT scores ---------
__global__ __launch_bounds__(256)
void k_mgemm3(const ushort_t* __restrict__ Ah, const ushort_t* __restrict__ Al, int lda,
              const ushort_t* __restrict__ Wh, const ushort_t* __restrict__ Wl, int ldw,
              float* __restrict__ Cf, int ldc,
              int Ndim, int K,
              const float* __restrict__ asrc, const float* __restrict__ adst,
              float* __restrict__ sb, float* __restrict__ tb, int Fsc) {
    constexpr int NTT = 4;
    __shared__ ushort_t AsH[64 * 40], BsH[64 * 40], AsL[64 * 40], BsL[64 * 40];
    int tid = threadIdx.x;
    int w = tid >> 6, lane = tid & 63;
    int quad = lane >> 4, l16 = lane & 15;
    int m0 = blockIdx.y * 64, n0 = blockIdx.x * 64;
    floatx4 acc[NTT] = {};
    for (int k0 = 0; k0 < K; k0 += 32) {
        {
            int row = tid >> 2, q = tid & 3;
            size_t go = (size_t)(m0 + row) * lda + k0 + q * 8;
            *(uint4_t*)&AsH[row * 40 + q * 8] = *(const uint4_t*)(Ah + go);
            *(uint4_t*)&AsL[row * 40 + q * 8] = *(const uint4_t*)(Al + go);
            uint4_t vh = {0, 0, 0, 0}, vl = {0, 0, 0, 0};
            size_t gw = (size_t)(n0 + row) * ldw + k0 + q * 8;
            if (n0 + row < Ndim) { vh = *(const uint4_t*)(Wh + gw); vl = *(const uint4_t*)(Wl + gw); }
            *(uint4_t*)&BsH[row * 40 + q * 8] = vh;
            *(uint4_t*)&BsL[row * 40 + q * 8] = vl;
        }
        __syncthreads();
        short8 ah, al;
        {
            int r = w * 16 + l16;
            ah = *(short8*)&AsH[r * 40 + quad * 8];
            al = *(short8*)&AsL[r * 40 + quad * 8];
        }
#pragma unroll
        for (int nt = 0; nt < NTT; nt++) {
            int r = nt * 16 + l16;
            short8 bh = *(short8*)&BsH[r * 40 + quad * 8];
            short8 bl = *(short8*)&BsL[r * 40 + quad * 8];
            acc[nt] = __builtin_amdgcn_mfma_f32_16x16x32_bf16(ah, bh, acc[nt], 0, 0, 0);
            acc[nt] = __builtin_amdgcn_mfma_f32_16x16x32_bf16(ah, bl, acc[nt], 0, 0, 0);
            acc[nt] = __builtin_amdgcn_mfma_f32_16x16x32_bf16(al, bh, acc[nt], 0, 0, 0);
        }
        __syncthreads();
    }
    if (asrc) {
        int h = n0 / Fsc;
#pragma unroll
        for (int r = 0; r < 4; r++) {
            float sp = 0.f, tp = 0.f;
#pragma unroll
            for (int nt = 0; nt < NTT; nt++) {
                float v = acc[nt][r];
                sp += v * asrc[n0 + nt * 16 + l16];
                tp += v * adst[n0 + nt * 16 + l16];
            }
#pragma unroll
            for (int off = 8; off >= 1; off >>= 1) {
                sp += __shfl_xor(sp, off, 64);
                tp += __shfl_xor(tp, off, 64);
            }
            if (l16 == 0) {
                int m = m0 + w * 16 + quad * 4 + r;
                sb[m * HEADS + h] = sp;
                tb[m * HEADS + h] = tp;
            }
        }
    }
#pragma unroll
    for (int nt = 0; nt < NTT; nt++) {
#pragma unroll
        for (int r = 0; r < 4; r++) {
            int m = m0 + w * 16 + quad * 4 + r;
            int n = n0 + nt * 16 + l16;
            if (n < Ndim) Cf[(size_t)m * ldc + n] = acc[nt][r];
        }
    }
}

// ---------------- exact-fp32 VALU GEMM for small N, K%64==0: LDS-tiled W ----------
template<int N_, int NPB>
__global__ __launch_bounds__(NPB * N_)
void k_vgemm(const float* __restrict__ A, int lda, int K_,
             const float* __restrict__ W, const float* __restrict__ bias,
             ushort_t* __restrict__ Ch, ushort_t* __restrict__ Cl, int ldh,
             float* __restrict__ Cf, int ldc, int relu) {
    constexpr int KT = 64;
    __shared__ float Ws[KT * N_];
    __shared__ float As[NPB * KT];
    int t = threadIdx.x;
    int n0 = blockIdx.x * NPB;
    int node = t / N_, j = t % N_;
    float acc = bias ? bias[j] : 0.f;
    for (int k0 = 0; k0 < K_; k0 += KT) {
        for (int idx = t; idx < KT * N_; idx += NPB * N_)
            Ws[idx] = W[(size_t)(k0 + idx / N_) * N_ + idx % N_];
        for (int idx = t; idx < NPB * KT; idx += NPB * N_)
            As[idx] = A[(size_t)(n0 + idx / KT) * lda + k0 + idx % KT];
        __syncthreads();
#pragma unroll
        for (int kk = 0; kk < KT; kk++)
            acc += As[node * KT + kk] * Ws[kk * N_ + j];
        __syncthreads();
    }
    if (relu && acc < 0.f) acc = 0.f;
    size_t m = n0 + node;
    if (Cf) Cf[m * ldc + j] = acc;
    if (Ch) {
        ushort_t h = f2bs(acc);
        Ch[m * ldh + j] = h;
        if (Cl) Cl[m * ldh + j] = f2bs(acc - bs2f(h));
    }
}

// ---------------- split-bf16 MFMA pairwise distances -> packed sort keys -----------
// sq computed in-kernel from staged tiles; nontemporal key stores (consumed once).
__global__ __launch_bounds__(256)
void k_mdist(const ushort_t* __restrict__ Lh, const ushort_t* __restrict__ Ll,
             int co, int C, uint_t* __restrict__ keys) {
    __shared__ ushort_t AsH[128 * 40], AsL[128 * 40], BsH[64 * 40], BsL[64 * 40];
    __shared__ float sqa[128], sqb[64];
    int tid = threadIdx.x;
    int w = tid >> 6, lane = tid & 63;
    int quad = lane >> 4, l16 = lane & 15;
    int b = blockIdx.z, cb = b * PP;
    int i0 = blockIdx.y * 128, j0 = blockIdx.x * 64;
    floatx4 acc[2][4] = {};
    float sacc = 0.f;
    for (int k0 = 0; k0 < C; k0 += 32) {
#pragma unroll
        for (int rep = 0; rep < 8; rep++) {
            int d = tid + rep * 256;
            int row = d >> 4, c2 = d & 15;
            size_t gi = ((size_t)(cb + i0 + row) * LDH + co + k0 + c2 * 2) >> 1;
            *(uint_t*)&AsH[row * 40 + c2 * 2] = ((const uint_t*)Lh)[gi];
            *(uint_t*)&AsL[row * 40 + c2 * 2] = ((const uint_t*)Ll)[gi];
        }
#pragma unroll
        for (int rep = 0; rep < 4; rep++) {
            int d = tid + rep * 256;
            int row = d >> 4, c2 = d & 15;
            size_t gi = ((size_t)(cb + j0 + row) * LDH + co + k0 + c2 * 2) >> 1;
            *(uint_t*)&BsH[row * 40 + c2 * 2] = ((const uint_t*)Lh)[gi];
            *(uint_t*)&BsL[row * 40 + c2 * 2] = ((const uint_t*)Ll)[gi];
        }
        __syncthreads();
        if (tid < 128) {
#pragma unroll
            for (int kk = 0; kk < 16; kk++) {
                uint_t ph = *(uint_t*)&AsH[tid * 40 + kk * 2];
                uint_t pl = *(uint_t*)&AsL[tid * 40 + kk * 2];
                float v0 = bs2f((ushort_t)(ph & 0xFFFFu)) + bs2f((ushort_t)(pl & 0xFFFFu));
                sacc += v0 * v0;
                float v1 = bs2f((ushort_t)(ph >> 16)) + bs2f((ushort_t)(pl >> 16));
                sacc += v1 * v1;
            }
        } else if (tid < 192) {
            int row = tid - 128;
#pragma unroll
            for (int kk = 0; kk < 16; kk++) {
                uint_t ph = *(uint_t*)&BsH[row * 40 + kk * 2];
                uint_t pl = *(uint_t*)&BsL[row * 40 + kk * 2];
                float v0 = bs2f((ushort_t)(ph & 0xFFFFu)) + bs2f((ushort_t)(pl & 0xFFFFu));
                sacc += v0 * v0;
                float v1 = bs2f((ushort_t)(ph >> 16)) + bs2f((ushort_t)(pl >> 16));
                sacc += v1 * v1;
            }
        }
        short8 ah[2], al[2];
#pragma unroll
        for (int mt = 0; mt < 2; mt++) {
            int r = w * 32 + mt * 16 + l16;
            ah[mt] = *(short8*)&AsH[r * 40 + quad * 8];
            al[mt] = *(short8*)&AsL[r * 40 + quad * 8];
        }
#pragma unroll
        for (int nt = 0; nt < 4; nt++) {
            int r = nt * 16 + l16;
            short8 bh = *(short8*)&BsH[r * 40 + quad * 8];
            short8 bl = *(short8*)&BsL[r * 40 + quad * 8];
#pragma unroll
            for (int mt = 0; mt < 2; mt++) {
                acc[mt][nt] = __builtin_amdgcn_mfma_f32_16x16x32_bf16(ah[mt], bh, acc[mt][nt], 0, 0, 0);
                acc[mt][nt] = __builtin_amdgcn_mfma_f32_16x16x32_bf16(ah[mt], bl, acc[mt][nt], 0, 0, 0);
                acc[mt][nt] = __builtin_amdgcn_mfma_f32_16x16x32_bf16(al[mt], bh, acc[mt][nt], 0, 0, 0);
            }
        }
        __syncthreads();
    }
    if (tid < 128) sqa[tid] = sacc;
    else if (tid < 192) sqb[tid - 128] = sacc;
    __syncthreads();
#pragma unroll
    for (int mt = 0; mt < 2; mt++) {
#pragma unroll
        for (int nt = 0; nt < 4; nt++) {
#pragma unroll
            for (int r = 0; r < 4; r++) {
                int li = w * 32 + mt * 16 + quad * 4 + r;
                int lj = nt * 16 + l16;
                int il = i0 + li, jl = j0 + lj;
                float dd = sqa[li] + sqb[lj] - 2.f * acc[mt][nt][r];
                dd = (il == jl) ? 3e9f : fmaxf(dd, 0.f);
                uint_t key = (__float_as_uint(dd) & 0xFFFFF800u) | (uint_t)jl;
                __builtin_nontemporal_store(key, &keys[(size_t)(cb + il) * PP + jl]);
            }
        }
    }
}

// ---------------- top-30 smallest per row via packed u32 keys ----------------
__global__ __launch_bounds__(256)
void k_topk(const uint_t* __restrict__ keys, int* __restrict__ nbr) {
    int r = blockIdx.x * 4 + (threadIdx.x >> 6);
    int lane = threadIdx.x & 63;
    int base = (r / PP) * PP;
    const uint_t* row = keys + (size_t)r * PP;
    uint_t v[32];
#pragma unroll
    for (int j = 0; j < 8; j++)
        *(uint4_t*)&v[j * 4] = *(const uint4_t*)(row + lane * 4 + j * 256);
    uint_t g[8];
#pragma unroll
    for (int j = 0; j < 8; j++)
        g[j] = min(min(v[j * 4], v[j * 4 + 1]), min(v[j * 4 + 2], v[j * 4 + 3]));
    uint_t lv = g[0];
#pragma unroll
    for (int j = 1; j < 8; j++) lv = min(lv, g[j]);
    for (int sel = 0; sel < KNN; sel++) {
        uint_t bk = lv;
#pragma unroll
        for (int off = 32; off > 0; off >>= 1)
            bk = min(bk, (uint_t)__shfl_xor((int)bk, off, 64));
        uint_t bks = __builtin_amdgcn_readfirstlane(bk);
        if (lane == 0) nbr[r * KTOT + sel] = base + (int)(bks & 0x7FFu);
        int grp = (int)((bks & 0x7FFu) >> 8);
#pragma unroll
        for (int jj = 0; jj < 8; jj++)
            if (grp == jj) {
#pragma unroll
                for (int t = 0; t < 4; t++)
                    v[jj * 4 + t] = (v[jj * 4 + t] == bks) ? 0xFFFFFFFFu : v[jj * 4 + t];
                g[jj] = min(min(v[jj * 4], v[jj * 4 + 1]), min(v[jj * 4 + 2], v[jj * 4 + 3]));
            }
        lv = g[0];
#pragma unroll
        for (int j = 1; j < 8; j++) lv = min(lv, g[j]);
    }
    if (lane == 0) nbr[r * KTOT + KNN] = r;
}

// ---------------- GAT source/target scores (stage 1 only) ----------------
__global__ void k_scores(const float* __restrict__ xh, int F,
                         const float* __restrict__ a_src,
                         const float* __restrict__ a_dst,
                         float* __restrict__ s, float* __restrict__ t) {
    int g = blockIdx.x * blockDim.x + threadIdx.x;
    if (g >= NPTS * HEADS) return;
    int n = g / HEADS, h = g % HEADS;
    const float* xr = xh + (size_t)n * (HEADS * F) + h * F;
    float ss = 0.f, tt = 0.f;
    for (int f = 0; f < F; f++) {
        float v = xr[f];
        ss += v * a_src[h * F + f];
        tt += v * a_dst[h * F + f];
    }
    s[g] = ss;
    t[g] = tt;
}

// ---------------- GAT edge-softmax + aggregate (fp32 out or bf16-hi out) ----------------
// XCD-aware block swizzle: cloud = bid & 3 keeps each cloud's xh slab in 2 XCD L2s.
__global__ void k_gat(const float* __restrict__ xh, int F,
                      const float* __restrict__ s, const float* __restrict__ t,
                      const int* __restrict__ nbr,
                      const float* __restrict__ bias,
                      float* __restrict__ outf, ushort_t* __restrict__ oh) {
    int HF = HEADS * F;
    __shared__ int srcs[KTOT];
    __shared__ float alpha[KTOT * HEADS];
    int i = (blockIdx.x & 3) * PP + (blockIdx.x >> 2);
    int tid = threadIdx.x;
    if (tid < KTOT) srcs[tid] = nbr[i * KTOT + tid];
    __syncthreads();
    if (tid < KTOT * HEADS) {
        int k = tid / HEADS, h = tid % HEADS;
        float e = s[srcs[k] * HEADS + h] + t[i * HEADS + h];
        if (e < 0.f) e *= 0.2f;
        alpha[tid] = e;
    }
    __syncthreads();
    if (tid < HEADS) {
        int h = tid;
        float m = -3e38f;
        for (int k = 0; k < KTOT; k++) m = fmaxf(m, alpha[k * HEADS + h]);
        float sum = 0.f;
        for (int k = 0; k < KTOT; k++) {
            float ex = expf(alpha[k * HEADS + h] - m);
            alpha[k * HEADS + h] = ex;
            sum += ex;
        }
        float inv = 1.f / sum;
        for (int k = 0; k < KTOT; k++) alpha[k * HEADS + h] *= inv;
    }
    __syncthreads();
    int h = tid / F;
    float acc = 0.f;
    for (int k = 0; k < KTOT; k++)
        acc += alpha[k * HEADS + h] * xh[(size_t)srcs[k] * HF + tid];
    float v = acc + bias[tid];
    if (oh) oh[(size_t)i * HF + tid] = f2bs(v);
    else outf[(size_t)i * HF + tid] = v;
}

// ---------------- gproj: decode fused column max + split-K matmul ----------------
__global__ void k_gproj(const uint_t* __restrict__ genc,
                        const float* __restrict__ mw1,
                        const float* __restrict__ mb1,
                        float* __restrict__ gproj) {
    __shared__ float gs[128];
    int kb = blockIdx.x;           // 8 blocks x 128 k
    int t = threadIdx.x;           // 256
    if (t < 128) gs[t] = fdec(genc[kb * 128 + t]);
    __syncthreads();
    float acc = (kb == 0) ? mb1[t] : 0.f;
    for (int k = 0; k < 128; k++)
        acc += gs[k] * mw1[(size_t)(326 + kb * 128 + k) * 256 + t];
    atomicAdd(&gproj[t], acc);
}

// ---------------- host side ----------------
struct WT { ushort_t *h, *l; int kp; };

extern "C" void kernel_launch(void* const* d_in, const int* in_sizes, int n_in,
                              void* d_out, int out_size, void* d_ws, size_t ws_size,
                              hipStream_t stream) {
    (void)in_sizes; (void)n_in; (void)out_size; (void)ws_size;
    const float* x    = (const float*)d_in[0];
    const float* pos  = (const float*)d_in[1];
    const float* w1   = (const float*)d_in[3];
    const float* as1  = (const float*)d_in[4];
    const float* ad1  = (const float*)d_in[5];
    const float* b1   = (const float*)d_in[6];
    const float* ml1w = (const float*)d_in[7];
    const float* ml1b = (const float*)d_in[8];
    const float* w2   = (const float*)d_in[9];
    const float* as2  = (const float*)d_in[10];
    const float* ad2  = (const float*)d_in[11];
    const float* b2   = (const float*)d_in[12];
    const float* ml2w = (const float*)d_in[13];
    const float* ml2b = (const float*)d_in[14];
    const float* w3   = (const float*)d_in[15];
    const float* as3  = (const float*)d_in[16];
    const float* ad3  = (const float*)d_in[17];
    const float* b3   = (const float*)d_in[18];
    const float* ml3w = (const float*)d_in[19];
    const float* ml3b = (const float*)d_in[20];
    const float* w4   = (const float*)d_in[21];
    const float* as4  = (const float*)d_in[22];
    const float* ad4  = (const float*)d_in[23];
    const float* b4   = (const float*)d_in[24];
    const float* ml4w = (const float*)d_in[25];
    const float* ml4b = (const float*)d_in[26];
    const float* few1 = (const float*)d_in[27];
    const float* feb1 = (const float*)d_in[28];
    const float* few2 = (const float*)d_in[29];
    const float* feb2 = (const float*)d_in[30];
    const float* mw1  = (const float*)d_in[31];
    const float* mb1  = (const float*)d_in[32];
    const float* mw2  = (const float*)d_in[33];
    const float* mb2  = (const float*)d_in[34];
    const float* mw3  = (const float*)d_in[35];
    const float* mb3  = (const float*)d_in[36];
    const float* mw4  = (const float*)d_in[37];
    const float* mb4  = (const float*)d_in[38];

    float* Wb = (float*)d_ws;
    size_t off = 0;
    auto alloc = [&](size_t n) { float* p = Wb + off; off += (n + 63) & ~(size_t)63; return p; };

    float*    dist = alloc((size_t)NPTS * PP);                  // 67 MB aliased region
    ushort_t* l4h  = (ushort_t*)alloc((size_t)NPTS * LDH / 2);
    ushort_t* l4l  = (ushort_t*)alloc((size_t)NPTS * LDH / 2);
    float*    gof  = alloc((size_t)NPTS * 384);                 // gat fp32 out (12.6MB)
    ushort_t* goh  = (ushort_t*)alloc((size_t)NPTS * 384 / 2);  // stage-4 gat bf16 out
    float* sbuf  = alloc((size_t)NPTS * HEADS);
    float* tbuf  = alloc((size_t)NPTS * HEADS);
    float* s4   = alloc((size_t)NPTS * HEADS);                  // stage-4 scores (atomic)
    float* t4   = alloc((size_t)NPTS * HEADS);
    uint_t* genc = (uint_t*)alloc(1024);                        // encoded col maxima
    float* gproj = alloc(256);
    int*   nbr   = (int*)alloc((size_t)NPTS * KTOT);
    ushort_t* wtpool = (ushort_t*)alloc(1831168 + 128);

    // aliases inside dist region (disjoint lifetimes):
    //   dkey (keys) lives between k_mdist and k_topk of each stage;
    //   xh is written AFTER topk consumed the keys, dead before next k_mdist.
    char* d0 = (char*)dist;
    uint_t*   dkey = (uint_t*)dist;
    float*    xh   = dist;
    ushort_t* hah  = (ushort_t*)d0;                             // fe1 out hi (16.8MB)
    ushort_t* bBh  = (ushort_t*)(d0 + (size_t)NPTS * 1024 * 2); // mw2 out hi
    ushort_t* bAh = (ushort_t*)gof;                             // mw1 out hi (gof dead after ml4)
    ushort_t* bCh = (ushort_t*)gof;                             // mw3 out hi (bAh dead)

    // ---- zero link4 planes + accumulators ----
    hipMemsetAsync(l4h, 0, (size_t)NPTS * LDH * 4, stream);
    hipMemsetAsync(gproj, 0, 256 * 4, stream);
    hipMemsetAsync(genc, 0, 1024 * 4, stream);
    hipMemsetAsync(s4, 0, (size_t)NPTS * HEADS * 2 * 4, stream);  // s4,t4 contiguous

    // ---- fused weight transpose+split (MFMA weights only) ----
    WArgs wa;
    WT wt[NSEG];
    {
        const float* srcs[NSEG] = {w2, w3, w4, ml4w, few1, few2, mw1, mw2, mw3, mw4};
        int Ks[NSEG] = {70, 134, 198, 384, 326, 1024, 326, 256, 256, 128};
        int Ns[NSEG] = {192, 192, 384, 128, 1024, 1024, 256, 256, 128, 50};
        size_t wo = 0; int tiles = 0;
        for (int i = 0; i < NSEG; i++) {
            int kp = (Ks[i] + 31) & ~31;
            wa.src[i] = srcs[i];
            wa.dst[i] = wtpool + wo;
            wa.K[i] = Ks[i]; wa.N[i] = Ns[i]; wa.Kp[i] = kp;
            wa.t0[i] = tiles;
            wt[i] = { wtpool + wo, wtpool + wo + (size_t)kp * Ns[i], kp };
            wo += (size_t)2 * kp * Ns[i];
            tiles += (kp / 32) * ((Ns[i] + 31) / 32);
        }
        k_wsplit_all<<<tiles, 256, 0, stream>>>(wa);
    }
    WT tw2 = wt[0], tw3 = wt[1], tw4 = wt[2], tml4 = wt[3], tfe1 = wt[4], tfe2 = wt[5],
       tmw1 = wt[6], tmw2 = wt[7], tmw3 = wt[8], tmw4 = wt[9];

    auto mg3 = [&](const ushort_t* Ah, const ushort_t* Al, int lda, WT t,
                   float* Cf, int ldc, int Nd, int K,
                   const float* asrc, const float* adst, float* sb, float* tb, int Fsc) {
        dim3 g((Nd + 63) / 64, NPTS / 64);
        k_mgemm3<<<g, 256, 0, stream>>>(Ah, Al, lda, t.h, t.l, t.kp, Cf, ldc, Nd, K,
                                        asrc, adst, sb, tb, Fsc);
    };
    auto mg1 = [&](int MT, int NT, const ushort_t* Ah, int lda, WT t,
                   float* Cf, int ldc, ushort_t* Ch, int ldhh,
                   int Nd, int K, const float* bb1, const float* bb2,
                   int relu, int lsm, uint_t* gmax,
                   const float* asrc, const float* adst, float* sb, float* tb,
                   int Fsc, int satomic) {
        dim3 g(NPTS / MT, (Nd + NT - 1) / NT);
        if (MT == 128 && NT == 64)
            k_mgemm1<128, 64><<<g, 256, 0, stream>>>(Ah, lda, t.h, t.kp, Cf, ldc, Ch, ldhh, Nd, K,
                bb1, bb2, relu, lsm, gmax, asrc, adst, sb, tb, Fsc, satomic);
        else
            k_mgemm1<64, 64><<<g, 256, 0, stream>>>(Ah, lda, t.h, t.kp, Cf, ldc, Ch, ldhh, Nd, K,
                bb1, bb2, relu, lsm, gmax, asrc, adst, sb, tb, Fsc, satomic);
    };

    dim3 dgrid(PP / 64, PP / 128, 4);
    k_build_x0<<<(NPTS * 6 + 255) / 256, 256, 0, stream>>>(x, pos, l4h, l4l);

    // ---- stage 1: knn on x0 (C=6); tw1 AFTER topk (xh aliases keys); GAT1 ----
    k_mdist<<<dgrid, 256, 0, stream>>>(l4h, l4l, 0, 6, dkey);
    k_topk<<<NPTS / 4, 256, 0, stream>>>(dkey, nbr);
    k_tw1<<<(NPTS * 192 + 255) / 256, 256, 0, stream>>>(x, pos, w1, xh);
    k_scores<<<(NPTS * HEADS + 255) / 256, 256, 0, stream>>>(xh, 64, as1, ad1, sbuf, tbuf);
    k_gat<<<NPTS, 192, 0, stream>>>(xh, 64, sbuf, tbuf, nbr, b1, gof, nullptr);
    k_vgemm<64, 4><<<NPTS / 4, 256, 0, stream>>>(gof, 192, 192, ml1w, ml1b,
        l4h + 6, l4l + 6, LDH, nullptr, 0, 0);

    // ---- stage 2: knn on x1 (C=64); tw2 fuses GAT2 scores; GAT2 -> x2 ----
    k_mdist<<<dgrid, 256, 0, stream>>>(l4h, l4l, 6, 64, dkey);
    k_topk<<<NPTS / 4, 256, 0, stream>>>(dkey, nbr);
    mg3(l4h, l4l, LDH, tw2, xh, 192, 192, 70, as2, ad2, sbuf, tbuf, 64);
    k_gat<<<NPTS, 192, 0, stream>>>(xh, 64, sbuf, tbuf, nbr, b2, gof, nullptr);
    k_vgemm<64, 4><<<NPTS / 4, 256, 0, stream>>>(gof, 192, 192, ml2w, ml2b,
        l4h + 70, l4l + 70, LDH, nullptr, 0, 0);

    // ---- stage 3: knn on x2 (C=64); tw3 fuses GAT3 scores; GAT3 -> x3 ----
    k_mdist<<<dgrid, 256, 0, stream>>>(l4h, l4l, 70, 64, dkey);
    k_topk<<<NPTS / 4, 256, 0, stream>>>(dkey, nbr);
    mg1(64, 64, l4h, LDH, tw3, xh, 192, nullptr, 0, 192, 134, nullptr, nullptr, 0, 0, nullptr,
        as3, ad3, sbuf, tbuf, 64, 0);
    k_gat<<<NPTS, 192, 0, stream>>>(xh, 64, sbuf, tbuf, nbr, b3, gof, nullptr);
    k_vgemm<64, 4><<<NPTS / 4, 256, 0, stream>>>(gof, 192, 192, ml3w, ml3b,
        l4h + 134, nullptr, LDH, nullptr, 0, 0);

    // ---- stage 4: tw4 fuses GAT4 scores (atomic partials into zeroed s4/t4) ----
    mg1(64, 64, l4h, LDH, tw4, xh, 384, nullptr, 0, 384, 198, nullptr, nullptr, 0, 0, nullptr,
        as4, ad4, s4, t4, 128, 1);
    k_gat<<<NPTS, 384, 0, stream>>>(xh, 128, s4, t4, nbr, b4, nullptr, goh);
    mg1(64, 64, goh, 384, tml4, nullptr, 0, l4h + 198, LDH, 128, 384, ml4b, nullptr, 0, 0, nullptr,
        nullptr, nullptr, nullptr, nullptr, 1, 0);

    // ---- fe_mlp: fe1 -> bf16 acts; fe2 -> fused global column max (no C write) ----
    mg1(128, 64, l4h, LDH, tfe1, nullptr, 0, hah, 1024, 1024, 326, feb1, nullptr, 1, 0, nullptr,
        nullptr, nullptr, nullptr, nullptr, 1, 0);
    mg1(128, 64, hah, 1024, tfe2, nullptr, 0, nullptr, 0, 1024, 1024, feb2, nullptr, 0, 0, genc,
        nullptr, nullptr, nullptr, nullptr, 1, 0);
    k_gproj<<<8, 256, 0, stream>>>(genc, mw1, mb1, gproj);

    // ---- head (bf16 tier; mw4 fuses log_softmax and writes d_out) ----
    mg1(128, 64, l4h, LDH, tmw1, nullptr, 0, bAh, 256, 256, 326, nullptr, gproj, 1, 0, nullptr,
        nullptr, nullptr, nullptr, nullptr, 1, 0);
    mg1(128, 64, bAh, 256, tmw2, nullptr, 0, bBh, 256, 256, 256, mb2, nullptr, 1, 0, nullptr,
        nullptr, nullptr, nullptr, nullptr, 1, 0);
    mg1(64, 64, bBh, 256, tmw3, nullptr, 0, bCh, 128, 128, 256, mb3, nullptr, 1, 0, nullptr,
        nullptr, nullptr, nullptr, nullptr, 1, 0);
    mg1(64, 64, bCh, 128, tmw4, (float*)d_out, 50, nullptr, 0, 50, 128, mb4, nullptr, 0, 1, nullptr,
        nullptr, nullptr, nullptr, nullptr, 1, 0);
}